// Round 12
// baseline (257.468 us; speedup 1.0000x reference)
//
#include <hip/hip_runtime.h>

#define NPTS 8192
#define SPTS 2048
#define BATCH 4
#define CO 256
#define TOTAL_ROWS (BATCH * NPTS)  // 32768

typedef __attribute__((ext_vector_type(4))) float f32x4;
typedef __attribute__((ext_vector_type(8))) short bf16x8s;
typedef __attribute__((ext_vector_type(4))) unsigned short u16x4;
typedef __attribute__((ext_vector_type(8))) unsigned short u16x8;

__device__ __forceinline__ unsigned short f2bf(float f) {
  unsigned int u = __float_as_uint(f);
  u += 0x7FFFu + ((u >> 16) & 1u);   // RNE
  return (unsigned short)(u >> 16);
}
__device__ __forceinline__ float bf2f(unsigned short h) {
  return __uint_as_float(((unsigned int)h) << 16);
}
__device__ __forceinline__ void gload_lds16(const void* g, void* l) {
  __builtin_amdgcn_global_load_lds((const __attribute__((address_space(1))) void*)g,
                                   (__attribute__((address_space(3))) void*)l, 16, 0, 0);
}

// packed layout for a [R][K] bf16 tensor (R%16==0, K%32==0), KT=K/32:
// elem(r,k) = ((r>>4)*KT + (k>>5))*512 + ((k>>3)&3)*128 + (r&15)*8 + (k&7)

// ---------------- convert + pack the three weight matrices ----------------
__global__ __launch_bounds__(256) void pack_w(
    const float* __restrict__ w1, const float* __restrict__ w2,
    const float* __restrict__ w3, unsigned short* __restrict__ o1,
    unsigned short* __restrict__ o2, unsigned short* __restrict__ o3) {
  int gid = blockIdx.x * 256 + threadIdx.x;  // one 8-elem chunk each
  const float* src;
  unsigned short* dst;
  int K, cl;
  if (gid < 12288) { src = w1; dst = o1; K = 384; cl = gid; }
  else if (gid < 20480) { src = w2; dst = o2; K = 256; cl = gid - 12288; }
  else if (gid < 28672) { src = w3; dst = o3; K = 256; cl = gid - 20480; }
  else return;
  int cpo = K >> 3;
  int o = cl / cpo, k0 = (cl - o * cpo) * 8;
  float4 a = *reinterpret_cast<const float4*>(src + (size_t)o * K + k0);
  float4 b = *reinterpret_cast<const float4*>(src + (size_t)o * K + k0 + 4);
  u16x8 v;
  v[0] = f2bf(a.x); v[1] = f2bf(a.y); v[2] = f2bf(a.z); v[3] = f2bf(a.w);
  v[4] = f2bf(b.x); v[5] = f2bf(b.y); v[6] = f2bf(b.z); v[7] = f2bf(b.w);
  int KT = K >> 5;
  size_t ad = ((size_t)(o >> 4) * KT + (k0 >> 5)) * 512 + ((k0 >> 3) & 3) * 128 + (o & 15) * 8;
  *reinterpret_cast<u16x8*>(dst + ad) = v;
}

// ---------------- tiled transpose: f32 [C][S] -> bf16, linear or packed ----------------
__global__ __launch_bounds__(256) void transpose_cb(
    const float* __restrict__ in, unsigned short* __restrict__ out,
    int C, int S, int KT, int packed) {
  __shared__ float LT[64][65];
  const int b = blockIdx.z;
  const int s0 = blockIdx.x * 64, c0 = blockIdx.y * 64;
  const float* inb = in + (size_t)b * C * S;
  const int t = threadIdx.x;
  const int cr = t >> 4, sq = t & 15;
  #pragma unroll
  for (int it = 0; it < 4; ++it) {
    int cc = cr + it * 16;
    float4 v = *reinterpret_cast<const float4*>(inb + (size_t)(c0 + cc) * S + s0 + sq * 4);
    LT[sq * 4 + 0][cc] = v.x; LT[sq * 4 + 1][cc] = v.y;
    LT[sq * 4 + 2][cc] = v.z; LT[sq * 4 + 3][cc] = v.w;
  }
  __syncthreads();
  const int sr = t >> 2, cq = t & 3;
  u16x8 o0v, o1v;
  #pragma unroll
  for (int k = 0; k < 8; ++k) o0v[k] = f2bf(LT[sr][cq * 16 + k]);
  #pragma unroll
  for (int k = 0; k < 8; ++k) o1v[k] = f2bf(LT[sr][cq * 16 + 8 + k]);
  if (packed) {
    size_t rg = (size_t)b * S + s0 + sr;
    int c = c0 + cq * 16;
    size_t ad = ((rg >> 4) * KT + (c >> 5)) * 512 + ((c >> 3) & 3) * 128 + (rg & 15) * 8;
    *reinterpret_cast<u16x8*>(out + ad) = o0v;
    *reinterpret_cast<u16x8*>(out + ad + 128) = o1v;  // c+8 -> hi+1
  } else {
    unsigned short* op = out + ((size_t)b * S + s0 + sr) * 256 + c0 + cq * 16;
    *reinterpret_cast<u16x8*>(op) = o0v;
    *reinterpret_cast<u16x8*>(op + 8) = o1v;
  }
}

// ---------------- pack xyz2 -> float4(x,y,z,|p|^2) ----------------
__global__ __launch_bounds__(256) void pack_xyz2(const float* __restrict__ xyz2,
                                                 float4* __restrict__ sptg) {
  int gid = blockIdx.x * 256 + threadIdx.x;  // 0..BATCH*SPTS-1
  const float* p = xyz2 + (size_t)gid * 3;
  float x = p[0], y = p[1], z = p[2];
  float b2 = __fadd_rn(__fadd_rn(__fmul_rn(x, x), __fmul_rn(y, y)), __fmul_rn(z, z));
  sptg[gid] = make_float4(x, y, z, b2);
}

// ---------------- KNN (k=3) + fused IDW gather ----------------
#define CSINS(q, dd, s)                                                    \
  do {                                                                     \
    float tt = dd; int ti = s;                                             \
    bool c0 = tt < d0[q];                                                  \
    float h = c0 ? d0[q] : tt; int hi_ = c0 ? i0[q] : ti;                  \
    d0[q] = c0 ? tt : d0[q];   i0[q] = c0 ? ti : i0[q];                    \
    tt = h; ti = hi_;                                                      \
    bool c1 = tt < d1[q];                                                  \
    h = c1 ? d1[q] : tt; hi_ = c1 ? i1[q] : ti;                            \
    d1[q] = c1 ? tt : d1[q];   i1[q] = c1 ? ti : i1[q];                    \
    tt = h; ti = hi_;                                                      \
    bool c2 = tt < d2[q];                                                  \
    d2[q] = c2 ? tt : d2[q];   i2[q] = c2 ? ti : i2[q];                    \
  } while (0)

// butterfly: packed u64 keys (orderable-d-bits << 32 | idx); lex(d,idx) == u64 <
#define INSK(x)                                                            \
  do {                                                                     \
    bool c0 = (x) < k0, c1 = (x) < k1, c2 = (x) < k2;                      \
    unsigned long long nk0 = c0 ? (x) : k0;                                \
    unsigned long long nk1 = c0 ? k0 : (c1 ? (x) : k1);                    \
    unsigned long long nk2 = c1 ? k1 : (c2 ? (x) : k2);                    \
    k0 = nk0; k1 = nk1; k2 = nk2;                                          \
  } while (0)

__device__ __forceinline__ unsigned long long packdi(float d, int i) {
  unsigned int b = __float_as_uint(d);
  unsigned int u = b ^ ((unsigned int)((int)b >> 31) | 0x80000000u);
  return ((unsigned long long)u << 32) | (unsigned int)i;
}
__device__ __forceinline__ float unpackd(unsigned long long k) {
  unsigned int u = (unsigned int)(k >> 32);
  unsigned int b = u ^ ((u & 0x80000000u) ? 0x80000000u : 0xFFFFFFFFu);
  return __uint_as_float(b);
}

__global__ __launch_bounds__(256) void knn_gather(
    const float* __restrict__ xyz1, const float4* __restrict__ sptg,
    const unsigned short* __restrict__ p2t, unsigned short* __restrict__ X1) {
  const int b = blockIdx.y, t = threadIdx.x;
  const int wave = t >> 6, lane = t & 63;
  const int nb = blockIdx.x * 16 + wave * 4;
  const float4* sp = sptg + (size_t)b * SPTS;

  float qx[4], qy[4], qz[4], a2[4];
  float d0[4], d1[4], d2[4];
  int i0[4], i1[4], i2[4];
  #pragma unroll
  for (int q = 0; q < 4; ++q) {
    const float* qp = xyz1 + ((size_t)b * NPTS + nb + q) * 3;
    qx[q] = qp[0]; qy[q] = qp[1]; qz[q] = qp[2];
    a2[q] = __fadd_rn(__fadd_rn(__fmul_rn(qx[q], qx[q]), __fmul_rn(qy[q], qy[q])),
                      __fmul_rn(qz[q], qz[q]));
    d0[q] = 1e30f; d1[q] = 1e30f; d2[q] = 1e30f;
    i0[q] = 0; i1[q] = 0; i2[q] = 0;
  }

  // 2 candidates per lane per iteration (s, s+64)
  #pragma unroll 2
  for (int it = 0; it < SPTS / 128; ++it) {
    int sA = it * 128 + lane;
    int sB = sA + 64;
    float4 pA = sp[sA];
    float4 pB = sp[sB];
    #pragma unroll
    for (int q = 0; q < 4; ++q) {
      float dotA = __fadd_rn(__fadd_rn(__fmul_rn(qx[q], pA.x), __fmul_rn(qy[q], pA.y)),
                             __fmul_rn(qz[q], pA.z));
      float dA = __fsub_rn(__fadd_rn(a2[q], pA.w), __fmul_rn(2.0f, dotA));
      float dotB = __fadd_rn(__fadd_rn(__fmul_rn(qx[q], pB.x), __fmul_rn(qy[q], pB.y)),
                             __fmul_rn(qz[q], pB.z));
      float dB = __fsub_rn(__fadd_rn(a2[q], pB.w), __fmul_rn(2.0f, dotB));
      CSINS(q, dA, sA);   // sA < sB: ascending order preserves lowest-index ties
      CSINS(q, dB, sB);
    }
  }

  #pragma unroll
  for (int q = 0; q < 4; ++q) {
    unsigned long long k0 = packdi(d0[q], i0[q]);
    unsigned long long k1 = packdi(d1[q], i1[q]);
    unsigned long long k2 = packdi(d2[q], i2[q]);
    // butterfly merge across 64 lanes on u64 keys; result in ALL lanes
    #pragma unroll
    for (int m = 1; m < 64; m <<= 1) {
      unsigned long long x0 = __shfl_xor(k0, m);
      unsigned long long x1 = __shfl_xor(k1, m);
      unsigned long long x2 = __shfl_xor(k2, m);
      INSK(x0); INSK(x1); INSK(x2);
    }
    int j0 = (int)(k0 & 0xFFFFFFFFu);
    int j1 = (int)(k1 & 0xFFFFFFFFu);
    int j2 = (int)(k2 & 0xFFFFFFFFu);
    float r0 = 1.0f / __fadd_rn(unpackd(k0), 1e-8f);
    float r1 = 1.0f / __fadd_rn(unpackd(k1), 1e-8f);
    float r2 = 1.0f / __fadd_rn(unpackd(k2), 1e-8f);
    float rs = __fadd_rn(__fadd_rn(r0, r1), r2);
    float w0 = r0 / rs, w1 = r1 / rs, w2 = r2 / rs;

    // fused IDW gather: lane handles 4 channels (8B), coalesced rows
    const unsigned short* rw0 = p2t + ((size_t)b * SPTS + j0) * 256 + lane * 4;
    const unsigned short* rw1 = p2t + ((size_t)b * SPTS + j1) * 256 + lane * 4;
    const unsigned short* rw2 = p2t + ((size_t)b * SPTS + j2) * 256 + lane * 4;
    u16x4 v0 = *reinterpret_cast<const u16x4*>(rw0);
    u16x4 v1 = *reinterpret_cast<const u16x4*>(rw1);
    u16x4 v2 = *reinterpret_cast<const u16x4*>(rw2);
    u16x4 o;
    #pragma unroll
    for (int e = 0; e < 4; ++e) {
      float f = w0 * bf2f(v0[e]) + w1 * bf2f(v1[e]) + w2 * bf2f(v2[e]);
      o[e] = f2bf(f);
    }
    size_t rg = (size_t)b * NPTS + nb + q;
    int ca = 128 + lane * 4;  // absolute k
    size_t ad = (rg >> 4) * 12 * 512 + (rg & 15) * 8 + (size_t)(ca >> 5) * 512 +
                ((ca >> 3) & 3) * 128 + (ca & 7);
    *reinterpret_cast<u16x4*>(X1 + ad) = o;
  }
}

// ---------------- packed bf16 MFMA GEMM v6: 8-wave blocks, 2-deep X prefetch ----
// 512 blocks (XCD swizzled), 512 threads = 8 waves. Block = 256 rows x 64 cols;
// wave owns 32 rows x 64 cols. W slice staged to LDS once; X fragments streamed
// from global with a 2-deep named register pipeline (xrA/xrB). 4 waves/SIMD.
template <int K, bool BNIN>
__global__ __launch_bounds__(512, 4) void gemm_packed(
    const unsigned short* __restrict__ Wp, const unsigned short* __restrict__ Xp,
    const float* __restrict__ ssp, const float* __restrict__ bias,
    unsigned short* __restrict__ Z, float* __restrict__ part) {
  constexpr int KT = K / 32;
  __shared__ unsigned short Ws[4 * KT * 512];  // 48KB (K=384) / 32KB (K=256)
  const int t = threadIdx.x, wave = t >> 6, lane = t & 63;
  const int lr = lane & 15, hi4 = lane >> 4;
  // bijective XCD-chunk swizzle: 512 blocks -> 8 chunks of 64
  const int id = blockIdx.x;
  const int wg = (id & 7) * 64 + (id >> 3);
  const int br = wg >> 2;   // 0..127 : 256-row panel
  const int cb = wg & 3;    // 0..3   : 64-col block

  // X prefetch for kt=0,1 (issued first; overlaps W staging latency)
  const unsigned short* Xb = Xp + ((size_t)(br * 16 + wave * 2) * KT) * 512 + lane * 8;
  u16x8 xrA0, xrA1, xrB0, xrB1;
  xrA0 = *reinterpret_cast<const u16x8*>(Xb);
  xrA1 = *reinterpret_cast<const u16x8*>(Xb + (size_t)KT * 512);
  xrB0 = *reinterpret_cast<const u16x8*>(Xb + 512);
  xrB1 = *reinterpret_cast<const u16x8*>(Xb + (size_t)KT * 512 + 512);

  // stage the 64-col W slice once (contiguous region), 512 threads
  const unsigned short* Wsrc = Wp + (size_t)cb * 4 * KT * 512;
  constexpr int WCH = 4 * KT * 512 / 8;  // 16B chunks
  #pragma unroll
  for (int i = 0; i < WCH / 512; ++i)
    gload_lds16(Wsrc + (size_t)(t + i * 512) * 8, Ws + (t + i * 512) * 8);
  __syncthreads();

  f32x4 acc[2][4];
  #pragma unroll
  for (int rr = 0; rr < 2; ++rr)
    #pragma unroll
    for (int ot = 0; ot < 4; ++ot) acc[rr][ot] = (f32x4)0.f;

  #pragma unroll
  for (int kt = 0; kt < KT; ++kt) {
    // rotate pipeline: consume xrA, shift xrB->xrA, prefetch kt+2 into xrB
    u16x8 xc0 = xrA0, xc1 = xrA1;
    xrA0 = xrB0; xrA1 = xrB1;
    if (kt + 2 < KT) {
      xrB0 = *reinterpret_cast<const u16x8*>(Xb + (size_t)(kt + 2) * 512);
      xrB1 = *reinterpret_cast<const u16x8*>(Xb + ((size_t)KT + kt + 2) * 512);
    }
    // convert current fragments (optional fused BN+ReLU)
    bf16x8s xf0, xf1;
    if constexpr (BNIN) {
      const int cbase = kt * 32 + hi4 * 8;
      f32x4 s0 = *reinterpret_cast<const f32x4*>(ssp + cbase);
      f32x4 s1 = *reinterpret_cast<const f32x4*>(ssp + cbase + 4);
      f32x4 h0 = *reinterpret_cast<const f32x4*>(ssp + 256 + cbase);
      f32x4 h1 = *reinterpret_cast<const f32x4*>(ssp + 256 + cbase + 4);
      u16x8 xo0, xo1;
      #pragma unroll
      for (int e = 0; e < 4; ++e) {
        xo0[e] = f2bf(fmaxf(s0[e] * bf2f(xc0[e]) + h0[e], 0.f));
        xo0[4 + e] = f2bf(fmaxf(s1[e] * bf2f(xc0[4 + e]) + h1[e], 0.f));
        xo1[e] = f2bf(fmaxf(s0[e] * bf2f(xc1[e]) + h0[e], 0.f));
        xo1[4 + e] = f2bf(fmaxf(s1[e] * bf2f(xc1[4 + e]) + h1[e], 0.f));
      }
      xf0 = *reinterpret_cast<bf16x8s*>(&xo0);
      xf1 = *reinterpret_cast<bf16x8s*>(&xo1);
    } else {
      xf0 = *reinterpret_cast<bf16x8s*>(&xc0);
      xf1 = *reinterpret_cast<bf16x8s*>(&xc1);
    }
    // W fragments from LDS + MFMA
    bf16x8s wf[4];
    #pragma unroll
    for (int ot = 0; ot < 4; ++ot)
      wf[ot] = *reinterpret_cast<const bf16x8s*>(Ws + (size_t)(ot * KT + kt) * 512 + lane * 8);
    #pragma unroll
    for (int ot = 0; ot < 4; ++ot) {
      acc[0][ot] = __builtin_amdgcn_mfma_f32_16x16x32_bf16(wf[ot], xf0, acc[0][ot], 0, 0, 0);
      acc[1][ot] = __builtin_amdgcn_mfma_f32_16x16x32_bf16(wf[ot], xf1, acc[1][ot], 0, 0, 0);
    }
  }

  // epilogue: bias, packed bf16 Z write, per-(32-row, wave) partial stats
  const size_t pbase = (size_t)(br * 8 + wave) * 512;
  #pragma unroll
  for (int ot = 0; ot < 4; ++ot) {
    const int o_c = cb * 64 + ot * 16 + hi4 * 4;
    f32x4 bv = *reinterpret_cast<const f32x4*>(bias + o_c);
    const int kto = o_c >> 5, hb = (o_c >> 3) & 3, e0 = o_c & 7;
    float sm[4] = {0.f, 0.f, 0.f, 0.f}, sq[4] = {0.f, 0.f, 0.f, 0.f};
    #pragma unroll
    for (int rr = 0; rr < 2; ++rr) {
      f32x4 v = acc[rr][ot] + bv;
      u16x4 oz;
      #pragma unroll
      for (int e = 0; e < 4; ++e) {
        oz[e] = f2bf(v[e]);
        sm[e] += v[e];
        sq[e] += v[e] * v[e];
      }
      size_t rtg = (size_t)br * 16 + wave * 2 + rr;
      *reinterpret_cast<u16x4*>(Z + (rtg * 8 + kto) * 512 + hb * 128 + lr * 8 + e0) = oz;
    }
    #pragma unroll
    for (int m = 8; m >= 1; m >>= 1) {
      #pragma unroll
      for (int e = 0; e < 4; ++e) {
        sm[e] += __shfl_xor(sm[e], m);
        sq[e] += __shfl_xor(sq[e], m);
      }
    }
    if (lr == 0) {
      f32x4 vs = {sm[0], sm[1], sm[2], sm[3]};
      f32x4 vq = {sq[0], sq[1], sq[2], sq[3]};
      *reinterpret_cast<f32x4*>(part + pbase + o_c) = vs;
      *reinterpret_cast<f32x4*>(part + pbase + 256 + o_c) = vq;
    }
  }
}

// ---------------- reduce partials (1024 strips) -> per-channel scale/shift ----------------
__global__ __launch_bounds__(256) void reduce_stats(
    const float* __restrict__ part, const float* __restrict__ gamma,
    const float* __restrict__ beta, float* __restrict__ ss) {
  __shared__ float red[8][64];
  const int t = threadIdx.x;
  const int strip = t >> 5, ch = t & 31;
  const int c = blockIdx.x * 32 + ch;
  float sm = 0.f, sq = 0.f;
  for (int i = strip; i < 1024; i += 8) {
    sm += part[(size_t)i * 512 + c];
    sq += part[(size_t)i * 512 + 256 + c];
  }
  red[strip][ch * 2] = sm;
  red[strip][ch * 2 + 1] = sq;
  __syncthreads();
  if (strip == 0) {
    #pragma unroll
    for (int k = 1; k < 8; ++k) {
      sm += red[k][ch * 2];
      sq += red[k][ch * 2 + 1];
    }
    const float inv = 1.0f / (float)TOTAL_ROWS;
    float mean = sm * inv;
    float var = sq * inv - mean * mean;
    float sc = gamma[c] * rsqrtf(var + 1e-5f);
    ss[c] = sc;
    ss[256 + c] = beta[c] - mean * sc;
  }
}

// ---------------- final: BN3 + residual(BN1 of Z1) + ReLU + transpose out ----------------
__global__ __launch_bounds__(256) void bn_res_out(
    const unsigned short* __restrict__ Z, const unsigned short* __restrict__ Zres,
    const float* __restrict__ ss_res, const float* __restrict__ ss_out,
    float* __restrict__ out) {
  __shared__ float LT[64][65];
  const int b = blockIdx.z, n0 = blockIdx.x * 64, o0 = blockIdx.y * 64;
  const int t = threadIdx.x;
  #pragma unroll
  for (int i = 0; i < 2; ++i) {
    int cid = t + i * 256;  // [rtl(2b)][ktl(1b)][hi(2b)][r(4b)]
    int r = cid & 15, hi = (cid >> 4) & 3, ktl = (cid >> 6) & 1, rtl = cid >> 7;
    size_t rt = (size_t)b * (NPTS / 16) + (n0 >> 4) + rtl;
    int kt = (o0 >> 5) + ktl;
    size_t ad = (rt * 8 + kt) * 512 + hi * 128 + r * 8;
    u16x8 z = *reinterpret_cast<const u16x8*>(Z + ad);
    u16x8 x = *reinterpret_cast<const u16x8*>(Zres + ad);
    int ob = o0 + ktl * 32 + hi * 8;
    #pragma unroll
    for (int e = 0; e < 8; ++e) {
      int c = ob + e;
      float xv = fmaxf(ss_res[c] * bf2f(x[e]) + ss_res[256 + c], 0.f);
      LT[ktl * 32 + hi * 8 + e][rtl * 16 + r] =
          fmaxf(ss_out[c] * bf2f(z[e]) + ss_out[256 + c] + xv, 0.f);
    }
  }
  __syncthreads();
  const int orow = t >> 2, nq = t & 3;
  float* op = out + ((size_t)b * CO + o0 + orow) * NPTS + n0 + nq * 16;
  #pragma unroll
  for (int j = 0; j < 4; ++j) {
    float4 v = make_float4(LT[orow][nq * 16 + j * 4 + 0], LT[orow][nq * 16 + j * 4 + 1],
                           LT[orow][nq * 16 + j * 4 + 2], LT[orow][nq * 16 + j * 4 + 3]);
    *reinterpret_cast<float4*>(op + j * 4) = v;
  }
}

extern "C" void kernel_launch(void* const* d_in, const int* in_sizes, int n_in,
                              void* d_out, int out_size, void* d_ws, size_t ws_size,
                              hipStream_t stream) {
  const float* xyz1    = (const float*)d_in[0];
  const float* xyz2    = (const float*)d_in[1];
  const float* points1 = (const float*)d_in[2];
  const float* points2 = (const float*)d_in[3];
  const float* fuse_w  = (const float*)d_in[4];
  const float* fuse_b  = (const float*)d_in[5];
  const float* fuse_g  = (const float*)d_in[6];
  const float* fuse_be = (const float*)d_in[7];
  const float* e1_w    = (const float*)d_in[8];
  const float* e1_b    = (const float*)d_in[9];
  const float* e1_g    = (const float*)d_in[10];
  const float* e1_be   = (const float*)d_in[11];
  const float* e2_w    = (const float*)d_in[12];
  const float* e2_b    = (const float*)d_in[13];
  const float* e2_g    = (const float*)d_in[14];
  const float* e2_be   = (const float*)d_in[15];
  float* out = (float*)d_out;

  char* w = (char*)d_ws;
  auto carve = [&](size_t bytes) {
    char* p = w;
    w += (bytes + 255) & ~(size_t)255;
    return p;
  };
  unsigned short* Wb1 = (unsigned short*)carve(98304 * 2);
  unsigned short* Wb2 = (unsigned short*)carve(65536 * 2);
  unsigned short* Wb3 = (unsigned short*)carve(65536 * 2);
  unsigned short* p2t = (unsigned short*)carve((size_t)BATCH * SPTS * 256 * 2);
  float4* sptg        = (float4*)carve((size_t)BATCH * SPTS * 16);
  unsigned short* X1  = (unsigned short*)carve((size_t)TOTAL_ROWS * 384 * 2);
  unsigned short* Z1  = (unsigned short*)carve((size_t)TOTAL_ROWS * 256 * 2);
  unsigned short* Z2  = (unsigned short*)carve((size_t)TOTAL_ROWS * 256 * 2);
  unsigned short* Z3  = (unsigned short*)carve((size_t)TOTAL_ROWS * 256 * 2);
  float* part         = (float*)carve((size_t)1024 * 512 * 4);  // 2MB partials
  float* ss           = (float*)carve(3 * 512 * 4);

  pack_w<<<dim3(112), 256, 0, stream>>>(fuse_w, e1_w, e2_w, Wb1, Wb2, Wb3);
  // points2 [256][2048] -> p2t bf16 linear [s][256]
  transpose_cb<<<dim3(32, 4, BATCH), 256, 0, stream>>>(points2, p2t, 256, SPTS, 0, 0);
  // points1 [128][8192] -> X1 packed (K=384, cols 0..127)
  transpose_cb<<<dim3(128, 2, BATCH), 256, 0, stream>>>(points1, X1, 128, NPTS, 12, 1);
  pack_xyz2<<<dim3(BATCH * SPTS / 256), 256, 0, stream>>>(xyz2, sptg);

  // KNN + fused IDW gather -> X1 packed (K=384, cols 128..383)
  knn_gather<<<dim3(NPTS / 16, BATCH), 256, 0, stream>>>(xyz1, sptg, p2t, X1);

  // stage 1: fuse (K=384), raw input
  gemm_packed<384, false><<<dim3(512), 512, 0, stream>>>(Wb1, X1, nullptr, fuse_b, Z1, part);
  reduce_stats<<<dim3(8), 256, 0, stream>>>(part, fuse_g, fuse_be, ss);

  // stage 2: net1 (K=256), BN1+ReLU fused into X path
  gemm_packed<256, true><<<dim3(512), 512, 0, stream>>>(Wb2, Z1, ss, e1_b, Z2, part);
  reduce_stats<<<dim3(8), 256, 0, stream>>>(part, e1_g, e1_be, ss + 512);

  // stage 3: net2 (K=256), BN2+ReLU fused into X path
  gemm_packed<256, true><<<dim3(512), 512, 0, stream>>>(Wb3, Z2, ss + 512, e2_b, Z3, part);
  reduce_stats<<<dim3(8), 256, 0, stream>>>(part, e2_g, e2_be, ss + 1024);

  // final: BN3(Z3) + residual BN1(Z1) + ReLU + transpose to out
  bn_res_out<<<dim3(NPTS / 64, 4, BATCH), 256, 0, stream>>>(Z3, Z1, ss, ss + 1024, out);
}

// Round 13
// 203.073 us; speedup vs baseline: 1.2679x; 1.2679x over previous
//
#include <hip/hip_runtime.h>

#define NPTS 8192
#define SPTS 2048
#define BATCH 4
#define CO 256
#define TOTAL_ROWS (BATCH * NPTS)  // 32768

typedef __attribute__((ext_vector_type(4))) float f32x4;
typedef __attribute__((ext_vector_type(8))) short bf16x8s;
typedef __attribute__((ext_vector_type(4))) unsigned short u16x4;
typedef __attribute__((ext_vector_type(8))) unsigned short u16x8;

__device__ __forceinline__ unsigned short f2bf(float f) {
  unsigned int u = __float_as_uint(f);
  u += 0x7FFFu + ((u >> 16) & 1u);   // RNE
  return (unsigned short)(u >> 16);
}
__device__ __forceinline__ float bf2f(unsigned short h) {
  return __uint_as_float(((unsigned int)h) << 16);
}
__device__ __forceinline__ void gload_lds16(const void* g, void* l) {
  __builtin_amdgcn_global_load_lds((const __attribute__((address_space(1))) void*)g,
                                   (__attribute__((address_space(3))) void*)l, 16, 0, 0);
}

// packed layout for a [R][K] bf16 tensor (R%16==0, K%32==0), KT=K/32:
// elem(r,k) = ((r>>4)*KT + (k>>5))*512 + ((k>>3)&3)*128 + (r&15)*8 + (k&7)

// ---------------- convert + pack the three weight matrices ----------------
__global__ __launch_bounds__(256) void pack_w(
    const float* __restrict__ w1, const float* __restrict__ w2,
    const float* __restrict__ w3, unsigned short* __restrict__ o1,
    unsigned short* __restrict__ o2, unsigned short* __restrict__ o3) {
  int gid = blockIdx.x * 256 + threadIdx.x;  // one 8-elem chunk each
  const float* src;
  unsigned short* dst;
  int K, cl;
  if (gid < 12288) { src = w1; dst = o1; K = 384; cl = gid; }
  else if (gid < 20480) { src = w2; dst = o2; K = 256; cl = gid - 12288; }
  else if (gid < 28672) { src = w3; dst = o3; K = 256; cl = gid - 20480; }
  else return;
  int cpo = K >> 3;
  int o = cl / cpo, k0 = (cl - o * cpo) * 8;
  float4 a = *reinterpret_cast<const float4*>(src + (size_t)o * K + k0);
  float4 b = *reinterpret_cast<const float4*>(src + (size_t)o * K + k0 + 4);
  u16x8 v;
  v[0] = f2bf(a.x); v[1] = f2bf(a.y); v[2] = f2bf(a.z); v[3] = f2bf(a.w);
  v[4] = f2bf(b.x); v[5] = f2bf(b.y); v[6] = f2bf(b.z); v[7] = f2bf(b.w);
  int KT = K >> 5;
  size_t ad = ((size_t)(o >> 4) * KT + (k0 >> 5)) * 512 + ((k0 >> 3) & 3) * 128 + (o & 15) * 8;
  *reinterpret_cast<u16x8*>(dst + ad) = v;
}

// ---------------- tiled transpose: f32 [C][S] -> bf16, linear or packed ----------------
__global__ __launch_bounds__(256) void transpose_cb(
    const float* __restrict__ in, unsigned short* __restrict__ out,
    int C, int S, int KT, int packed) {
  __shared__ float LT[64][65];
  const int b = blockIdx.z;
  const int s0 = blockIdx.x * 64, c0 = blockIdx.y * 64;
  const float* inb = in + (size_t)b * C * S;
  const int t = threadIdx.x;
  const int cr = t >> 4, sq = t & 15;
  #pragma unroll
  for (int it = 0; it < 4; ++it) {
    int cc = cr + it * 16;
    float4 v = *reinterpret_cast<const float4*>(inb + (size_t)(c0 + cc) * S + s0 + sq * 4);
    LT[sq * 4 + 0][cc] = v.x; LT[sq * 4 + 1][cc] = v.y;
    LT[sq * 4 + 2][cc] = v.z; LT[sq * 4 + 3][cc] = v.w;
  }
  __syncthreads();
  const int sr = t >> 2, cq = t & 3;
  u16x8 o0v, o1v;
  #pragma unroll
  for (int k = 0; k < 8; ++k) o0v[k] = f2bf(LT[sr][cq * 16 + k]);
  #pragma unroll
  for (int k = 0; k < 8; ++k) o1v[k] = f2bf(LT[sr][cq * 16 + 8 + k]);
  if (packed) {
    size_t rg = (size_t)b * S + s0 + sr;
    int c = c0 + cq * 16;
    size_t ad = ((rg >> 4) * KT + (c >> 5)) * 512 + ((c >> 3) & 3) * 128 + (rg & 15) * 8;
    *reinterpret_cast<u16x8*>(out + ad) = o0v;
    *reinterpret_cast<u16x8*>(out + ad + 128) = o1v;  // c+8 -> hi+1
  } else {
    unsigned short* op = out + ((size_t)b * S + s0 + sr) * 256 + c0 + cq * 16;
    *reinterpret_cast<u16x8*>(op) = o0v;
    *reinterpret_cast<u16x8*>(op + 8) = o1v;
  }
}

// ---------------- pack xyz2 -> float4(x,y,z,|p|^2) ----------------
__global__ __launch_bounds__(256) void pack_xyz2(const float* __restrict__ xyz2,
                                                 float4* __restrict__ sptg) {
  int gid = blockIdx.x * 256 + threadIdx.x;  // 0..BATCH*SPTS-1
  const float* p = xyz2 + (size_t)gid * 3;
  float x = p[0], y = p[1], z = p[2];
  float b2 = __fadd_rn(__fadd_rn(__fmul_rn(x, x), __fmul_rn(y, y)), __fmul_rn(z, z));
  sptg[gid] = make_float4(x, y, z, b2);
}

// ---------------- KNN (k=3) + fused IDW gather ----------------
#define CSINS(q, dd, s)                                                    \
  do {                                                                     \
    float tt = dd; int ti = s;                                             \
    bool c0 = tt < d0[q];                                                  \
    float h = c0 ? d0[q] : tt; int hi_ = c0 ? i0[q] : ti;                  \
    d0[q] = c0 ? tt : d0[q];   i0[q] = c0 ? ti : i0[q];                    \
    tt = h; ti = hi_;                                                      \
    bool c1 = tt < d1[q];                                                  \
    h = c1 ? d1[q] : tt; hi_ = c1 ? i1[q] : ti;                            \
    d1[q] = c1 ? tt : d1[q];   i1[q] = c1 ? ti : i1[q];                    \
    tt = h; ti = hi_;                                                      \
    bool c2 = tt < d2[q];                                                  \
    d2[q] = c2 ? tt : d2[q];   i2[q] = c2 ? ti : i2[q];                    \
  } while (0)

// butterfly: packed u64 keys (orderable-d-bits << 32 | idx); lex(d,idx) == u64 <
#define INSK(x)                                                            \
  do {                                                                     \
    bool c0 = (x) < k0, c1 = (x) < k1, c2 = (x) < k2;                      \
    unsigned long long nk0 = c0 ? (x) : k0;                                \
    unsigned long long nk1 = c0 ? k0 : (c1 ? (x) : k1);                    \
    unsigned long long nk2 = c1 ? k1 : (c2 ? (x) : k2);                    \
    k0 = nk0; k1 = nk1; k2 = nk2;                                          \
  } while (0)

__device__ __forceinline__ unsigned long long packdi(float d, int i) {
  unsigned int b = __float_as_uint(d);
  unsigned int u = b ^ ((unsigned int)((int)b >> 31) | 0x80000000u);
  return ((unsigned long long)u << 32) | (unsigned int)i;
}
__device__ __forceinline__ float unpackd(unsigned long long k) {
  unsigned int u = (unsigned int)(k >> 32);
  unsigned int b = u ^ ((u & 0x80000000u) ? 0x80000000u : 0xFFFFFFFFu);
  return __uint_as_float(b);
}

__global__ __launch_bounds__(256) void knn_gather(
    const float* __restrict__ xyz1, const float4* __restrict__ sptg,
    const unsigned short* __restrict__ p2t, unsigned short* __restrict__ X1) {
  const int b = blockIdx.y, t = threadIdx.x;
  const int wave = t >> 6, lane = t & 63;
  const int nb = blockIdx.x * 16 + wave * 4;
  const float4* sp = sptg + (size_t)b * SPTS;

  float qx[4], qy[4], qz[4], a2[4];
  float d0[4], d1[4], d2[4];
  int i0[4], i1[4], i2[4];
  #pragma unroll
  for (int q = 0; q < 4; ++q) {
    const float* qp = xyz1 + ((size_t)b * NPTS + nb + q) * 3;
    qx[q] = qp[0]; qy[q] = qp[1]; qz[q] = qp[2];
    a2[q] = __fadd_rn(__fadd_rn(__fmul_rn(qx[q], qx[q]), __fmul_rn(qy[q], qy[q])),
                      __fmul_rn(qz[q], qz[q]));
    d0[q] = 1e30f; d1[q] = 1e30f; d2[q] = 1e30f;
    i0[q] = 0; i1[q] = 0; i2[q] = 0;
  }

  // 2 candidates per lane per iteration (s, s+64)
  #pragma unroll 2
  for (int it = 0; it < SPTS / 128; ++it) {
    int sA = it * 128 + lane;
    int sB = sA + 64;
    float4 pA = sp[sA];
    float4 pB = sp[sB];
    #pragma unroll
    for (int q = 0; q < 4; ++q) {
      float dotA = __fadd_rn(__fadd_rn(__fmul_rn(qx[q], pA.x), __fmul_rn(qy[q], pA.y)),
                             __fmul_rn(qz[q], pA.z));
      float dA = __fsub_rn(__fadd_rn(a2[q], pA.w), __fmul_rn(2.0f, dotA));
      float dotB = __fadd_rn(__fadd_rn(__fmul_rn(qx[q], pB.x), __fmul_rn(qy[q], pB.y)),
                             __fmul_rn(qz[q], pB.z));
      float dB = __fsub_rn(__fadd_rn(a2[q], pB.w), __fmul_rn(2.0f, dotB));
      CSINS(q, dA, sA);   // sA < sB: ascending order preserves lowest-index ties
      CSINS(q, dB, sB);
    }
  }

  #pragma unroll
  for (int q = 0; q < 4; ++q) {
    unsigned long long k0 = packdi(d0[q], i0[q]);
    unsigned long long k1 = packdi(d1[q], i1[q]);
    unsigned long long k2 = packdi(d2[q], i2[q]);
    // butterfly merge across 64 lanes on u64 keys; result in ALL lanes
    #pragma unroll
    for (int m = 1; m < 64; m <<= 1) {
      unsigned long long x0 = __shfl_xor(k0, m);
      unsigned long long x1 = __shfl_xor(k1, m);
      unsigned long long x2 = __shfl_xor(k2, m);
      INSK(x0); INSK(x1); INSK(x2);
    }
    int j0 = (int)(k0 & 0xFFFFFFFFu);
    int j1 = (int)(k1 & 0xFFFFFFFFu);
    int j2 = (int)(k2 & 0xFFFFFFFFu);
    float r0 = 1.0f / __fadd_rn(unpackd(k0), 1e-8f);
    float r1 = 1.0f / __fadd_rn(unpackd(k1), 1e-8f);
    float r2 = 1.0f / __fadd_rn(unpackd(k2), 1e-8f);
    float rs = __fadd_rn(__fadd_rn(r0, r1), r2);
    float w0 = r0 / rs, w1 = r1 / rs, w2 = r2 / rs;

    // fused IDW gather: lane handles 4 channels (8B), coalesced rows
    const unsigned short* rw0 = p2t + ((size_t)b * SPTS + j0) * 256 + lane * 4;
    const unsigned short* rw1 = p2t + ((size_t)b * SPTS + j1) * 256 + lane * 4;
    const unsigned short* rw2 = p2t + ((size_t)b * SPTS + j2) * 256 + lane * 4;
    u16x4 v0 = *reinterpret_cast<const u16x4*>(rw0);
    u16x4 v1 = *reinterpret_cast<const u16x4*>(rw1);
    u16x4 v2 = *reinterpret_cast<const u16x4*>(rw2);
    u16x4 o;
    #pragma unroll
    for (int e = 0; e < 4; ++e) {
      float f = w0 * bf2f(v0[e]) + w1 * bf2f(v1[e]) + w2 * bf2f(v2[e]);
      o[e] = f2bf(f);
    }
    size_t rg = (size_t)b * NPTS + nb + q;
    int ca = 128 + lane * 4;  // absolute k
    size_t ad = (rg >> 4) * 12 * 512 + (rg & 15) * 8 + (size_t)(ca >> 5) * 512 +
                ((ca >> 3) & 3) * 128 + (ca & 7);
    *reinterpret_cast<u16x4*>(X1 + ad) = o;
  }
}

// ---------------- packed bf16 MFMA GEMM v7 (= v5 with 3-deep X prefetch) ----
// 512 blocks (XCD swizzled). Block = 256 rows x 64 cols, 4 waves each 64r x 64c.
// W slice staged to LDS once; X fragments streamed from global with a 3-deep
// register pipeline (slot = kt%3, compile-time after full unroll).
// BNIN: X elements are prev-layer Z; apply y = max(sc*z+sh, 0) inline.
template <int K, bool BNIN>
__global__ __launch_bounds__(256) void gemm_packed(
    const unsigned short* __restrict__ Wp, const unsigned short* __restrict__ Xp,
    const float* __restrict__ ssp, const float* __restrict__ bias,
    unsigned short* __restrict__ Z, float* __restrict__ part) {
  constexpr int KT = K / 32;
  __shared__ unsigned short Ws[4 * KT * 512];  // 48KB (K=384) / 32KB (K=256)
  const int t = threadIdx.x, wave = t >> 6, lane = t & 63;
  const int lr = lane & 15, hi4 = lane >> 4;
  // bijective XCD-chunk swizzle: 512 blocks -> 8 chunks of 64
  const int id = blockIdx.x;
  const int wg = (id & 7) * 64 + (id >> 3);
  const int br = wg >> 2;   // 0..127 : 256-row panel
  const int cb = wg & 3;    // 0..3   : 64-col block

  // 3-deep X prefetch (kt=0,1,2), issued BEFORE the W-stage barrier
  const unsigned short* Xb = Xp + ((size_t)(br * 16 + wave * 4) * KT) * 512 + lane * 8;
  u16x8 xp[3][4];
  #pragma unroll
  for (int d = 0; d < 3; ++d)
    #pragma unroll
    for (int rr = 0; rr < 4; ++rr)
      xp[d][rr] = *reinterpret_cast<const u16x8*>(Xb + ((size_t)rr * KT + d) * 512);

  // stage the 64-col W slice once (contiguous region)
  const unsigned short* Wsrc = Wp + (size_t)cb * 4 * KT * 512;
  constexpr int WCH = 4 * KT * 512 / 8;  // 16B chunks
  #pragma unroll
  for (int i = 0; i < WCH / 256; ++i)
    gload_lds16(Wsrc + (size_t)(t + i * 256) * 8, Ws + (t + i * 256) * 8);
  __syncthreads();

  f32x4 acc[4][4];
  #pragma unroll
  for (int rr = 0; rr < 4; ++rr)
    #pragma unroll
    for (int ot = 0; ot < 4; ++ot) acc[rr][ot] = (f32x4)0.f;

  #pragma unroll
  for (int kt = 0; kt < KT; ++kt) {
    const int slot = kt % 3;  // compile-time constant after full unroll
    // snapshot current fragments, then refill slot with kt+3
    u16x8 xc[4];
    #pragma unroll
    for (int rr = 0; rr < 4; ++rr) xc[rr] = xp[slot][rr];
    if (kt + 3 < KT) {
      #pragma unroll
      for (int rr = 0; rr < 4; ++rr)
        xp[slot][rr] = *reinterpret_cast<const u16x8*>(Xb + ((size_t)rr * KT + kt + 3) * 512);
    }
    // convert current fragments (optional fused BN+ReLU)
    bf16x8s xf[4];
    if constexpr (BNIN) {
      const int cbase = kt * 32 + hi4 * 8;
      f32x4 s0 = *reinterpret_cast<const f32x4*>(ssp + cbase);
      f32x4 s1 = *reinterpret_cast<const f32x4*>(ssp + cbase + 4);
      f32x4 h0 = *reinterpret_cast<const f32x4*>(ssp + 256 + cbase);
      f32x4 h1 = *reinterpret_cast<const f32x4*>(ssp + 256 + cbase + 4);
      #pragma unroll
      for (int rr = 0; rr < 4; ++rr) {
        u16x8 xo;
        #pragma unroll
        for (int e = 0; e < 4; ++e)
          xo[e] = f2bf(fmaxf(s0[e] * bf2f(xc[rr][e]) + h0[e], 0.f));
        #pragma unroll
        for (int e = 0; e < 4; ++e)
          xo[4 + e] = f2bf(fmaxf(s1[e] * bf2f(xc[rr][4 + e]) + h1[e], 0.f));
        xf[rr] = *reinterpret_cast<bf16x8s*>(&xo);
      }
    } else {
      #pragma unroll
      for (int rr = 0; rr < 4; ++rr)
        xf[rr] = *reinterpret_cast<bf16x8s*>(&xc[rr]);
    }
    // W fragments from LDS + MFMA
    bf16x8s wf[4];
    #pragma unroll
    for (int ot = 0; ot < 4; ++ot)
      wf[ot] = *reinterpret_cast<const bf16x8s*>(Ws + (size_t)(ot * KT + kt) * 512 + lane * 8);
    #pragma unroll
    for (int rr = 0; rr < 4; ++rr)
      #pragma unroll
      for (int ot = 0; ot < 4; ++ot)
        acc[rr][ot] =
            __builtin_amdgcn_mfma_f32_16x16x32_bf16(wf[ot], xf[rr], acc[rr][ot], 0, 0, 0);
  }

  // epilogue: bias, packed bf16 Z write, per-(256-row-panel, wave) partial stats
  const size_t pbase = (size_t)(br * 4 + wave) * 512;
  #pragma unroll
  for (int ot = 0; ot < 4; ++ot) {
    const int o_c = cb * 64 + ot * 16 + hi4 * 4;
    f32x4 bv = *reinterpret_cast<const f32x4*>(bias + o_c);
    const int kto = o_c >> 5, hb = (o_c >> 3) & 3, e0 = o_c & 7;
    float sm[4] = {0.f, 0.f, 0.f, 0.f}, sq[4] = {0.f, 0.f, 0.f, 0.f};
    #pragma unroll
    for (int rr = 0; rr < 4; ++rr) {
      f32x4 v = acc[rr][ot] + bv;
      u16x4 oz;
      #pragma unroll
      for (int e = 0; e < 4; ++e) {
        oz[e] = f2bf(v[e]);
        sm[e] += v[e];
        sq[e] += v[e] * v[e];
      }
      size_t rtg = (size_t)br * 16 + wave * 4 + rr;
      *reinterpret_cast<u16x4*>(Z + (rtg * 8 + kto) * 512 + hb * 128 + lr * 8 + e0) = oz;
    }
    #pragma unroll
    for (int m = 8; m >= 1; m >>= 1) {
      #pragma unroll
      for (int e = 0; e < 4; ++e) {
        sm[e] += __shfl_xor(sm[e], m);
        sq[e] += __shfl_xor(sq[e], m);
      }
    }
    if (lr == 0) {
      f32x4 vs = {sm[0], sm[1], sm[2], sm[3]};
      f32x4 vq = {sq[0], sq[1], sq[2], sq[3]};
      *reinterpret_cast<f32x4*>(part + pbase + o_c) = vs;
      *reinterpret_cast<f32x4*>(part + pbase + 256 + o_c) = vq;
    }
  }
}

// ---------------- reduce partials (512 strips) -> per-channel scale/shift ----------------
__global__ __launch_bounds__(256) void reduce_stats(
    const float* __restrict__ part, const float* __restrict__ gamma,
    const float* __restrict__ beta, float* __restrict__ ss) {
  __shared__ float red[8][64];
  const int t = threadIdx.x;
  const int strip = t >> 5, ch = t & 31;
  const int c = blockIdx.x * 32 + ch;
  float sm = 0.f, sq = 0.f;
  for (int i = strip; i < 512; i += 8) {
    sm += part[(size_t)i * 512 + c];
    sq += part[(size_t)i * 512 + 256 + c];
  }
  red[strip][ch * 2] = sm;
  red[strip][ch * 2 + 1] = sq;
  __syncthreads();
  if (strip == 0) {
    #pragma unroll
    for (int k = 1; k < 8; ++k) {
      sm += red[k][ch * 2];
      sq += red[k][ch * 2 + 1];
    }
    const float inv = 1.0f / (float)TOTAL_ROWS;
    float mean = sm * inv;
    float var = sq * inv - mean * mean;
    float sc = gamma[c] * rsqrtf(var + 1e-5f);
    ss[c] = sc;
    ss[256 + c] = beta[c] - mean * sc;
  }
}

// ---------------- final: BN3 + residual(BN1 of Z1) + ReLU + transpose out ----------------
__global__ __launch_bounds__(256) void bn_res_out(
    const unsigned short* __restrict__ Z, const unsigned short* __restrict__ Zres,
    const float* __restrict__ ss_res, const float* __restrict__ ss_out,
    float* __restrict__ out) {
  __shared__ float LT[64][65];
  const int b = blockIdx.z, n0 = blockIdx.x * 64, o0 = blockIdx.y * 64;
  const int t = threadIdx.x;
  #pragma unroll
  for (int i = 0; i < 2; ++i) {
    int cid = t + i * 256;  // [rtl(2b)][ktl(1b)][hi(2b)][r(4b)]
    int r = cid & 15, hi = (cid >> 4) & 3, ktl = (cid >> 6) & 1, rtl = cid >> 7;
    size_t rt = (size_t)b * (NPTS / 16) + (n0 >> 4) + rtl;
    int kt = (o0 >> 5) + ktl;
    size_t ad = (rt * 8 + kt) * 512 + hi * 128 + r * 8;
    u16x8 z = *reinterpret_cast<const u16x8*>(Z + ad);
    u16x8 x = *reinterpret_cast<const u16x8*>(Zres + ad);
    int ob = o0 + ktl * 32 + hi * 8;
    #pragma unroll
    for (int e = 0; e < 8; ++e) {
      int c = ob + e;
      float xv = fmaxf(ss_res[c] * bf2f(x[e]) + ss_res[256 + c], 0.f);
      LT[ktl * 32 + hi * 8 + e][rtl * 16 + r] =
          fmaxf(ss_out[c] * bf2f(z[e]) + ss_out[256 + c] + xv, 0.f);
    }
  }
  __syncthreads();
  const int orow = t >> 2, nq = t & 3;
  float* op = out + ((size_t)b * CO + o0 + orow) * NPTS + n0 + nq * 16;
  #pragma unroll
  for (int j = 0; j < 4; ++j) {
    float4 v = make_float4(LT[orow][nq * 16 + j * 4 + 0], LT[orow][nq * 16 + j * 4 + 1],
                           LT[orow][nq * 16 + j * 4 + 2], LT[orow][nq * 16 + j * 4 + 3]);
    *reinterpret_cast<float4*>(op + j * 4) = v;
  }
}

extern "C" void kernel_launch(void* const* d_in, const int* in_sizes, int n_in,
                              void* d_out, int out_size, void* d_ws, size_t ws_size,
                              hipStream_t stream) {
  const float* xyz1    = (const float*)d_in[0];
  const float* xyz2    = (const float*)d_in[1];
  const float* points1 = (const float*)d_in[2];
  const float* points2 = (const float*)d_in[3];
  const float* fuse_w  = (const float*)d_in[4];
  const float* fuse_b  = (const float*)d_in[5];
  const float* fuse_g  = (const float*)d_in[6];
  const float* fuse_be = (const float*)d_in[7];
  const float* e1_w    = (const float*)d_in[8];
  const float* e1_b    = (const float*)d_in[9];
  const float* e1_g    = (const float*)d_in[10];
  const float* e1_be   = (const float*)d_in[11];
  const float* e2_w    = (const float*)d_in[12];
  const float* e2_b    = (const float*)d_in[13];
  const float* e2_g    = (const float*)d_in[14];
  const float* e2_be   = (const float*)d_in[15];
  float* out = (float*)d_out;

  char* w = (char*)d_ws;
  auto carve = [&](size_t bytes) {
    char* p = w;
    w += (bytes + 255) & ~(size_t)255;
    return p;
  };
  unsigned short* Wb1 = (unsigned short*)carve(98304 * 2);
  unsigned short* Wb2 = (unsigned short*)carve(65536 * 2);
  unsigned short* Wb3 = (unsigned short*)carve(65536 * 2);
  unsigned short* p2t = (unsigned short*)carve((size_t)BATCH * SPTS * 256 * 2);
  float4* sptg        = (float4*)carve((size_t)BATCH * SPTS * 16);
  unsigned short* X1  = (unsigned short*)carve((size_t)TOTAL_ROWS * 384 * 2);
  unsigned short* Z1  = (unsigned short*)carve((size_t)TOTAL_ROWS * 256 * 2);
  unsigned short* Z2  = (unsigned short*)carve((size_t)TOTAL_ROWS * 256 * 2);
  unsigned short* Z3  = (unsigned short*)carve((size_t)TOTAL_ROWS * 256 * 2);
  float* part         = (float*)carve((size_t)512 * 512 * 4);  // 1MB partials
  float* ss           = (float*)carve(3 * 512 * 4);

  pack_w<<<dim3(112), 256, 0, stream>>>(fuse_w, e1_w, e2_w, Wb1, Wb2, Wb3);
  // points2 [256][2048] -> p2t bf16 linear [s][256]
  transpose_cb<<<dim3(32, 4, BATCH), 256, 0, stream>>>(points2, p2t, 256, SPTS, 0, 0);
  // points1 [128][8192] -> X1 packed (K=384, cols 0..127)
  transpose_cb<<<dim3(128, 2, BATCH), 256, 0, stream>>>(points1, X1, 128, NPTS, 12, 1);
  pack_xyz2<<<dim3(BATCH * SPTS / 256), 256, 0, stream>>>(xyz2, sptg);

  // KNN + fused IDW gather -> X1 packed (K=384, cols 128..383)
  knn_gather<<<dim3(NPTS / 16, BATCH), 256, 0, stream>>>(xyz1, sptg, p2t, X1);

  // stage 1: fuse (K=384), raw input
  gemm_packed<384, false><<<dim3(512), 256, 0, stream>>>(Wb1, X1, nullptr, fuse_b, Z1, part);
  reduce_stats<<<dim3(8), 256, 0, stream>>>(part, fuse_g, fuse_be, ss);

  // stage 2: net1 (K=256), BN1+ReLU fused into X path
  gemm_packed<256, true><<<dim3(512), 256, 0, stream>>>(Wb2, Z1, ss, e1_b, Z2, part);
  reduce_stats<<<dim3(8), 256, 0, stream>>>(part, e1_g, e1_be, ss + 512);

  // stage 3: net2 (K=256), BN2+ReLU fused into X path
  gemm_packed<256, true><<<dim3(512), 256, 0, stream>>>(Wb3, Z2, ss + 512, e2_b, Z3, part);
  reduce_stats<<<dim3(8), 256, 0, stream>>>(part, e2_g, e2_be, ss + 1024);

  // final: BN3(Z3) + residual BN1(Z1) + ReLU + transpose to out
  bn_res_out<<<dim3(NPTS / 64, 4, BATCH), 256, 0, stream>>>(Z3, Z1, ss, ss + 1024, out);
}

// Round 14
// 189.969 us; speedup vs baseline: 1.3553x; 1.0690x over previous
//
#include <hip/hip_runtime.h>

#define NPTS 8192
#define SPTS 2048
#define BATCH 4
#define CO 256
#define TOTAL_ROWS (BATCH * NPTS)  // 32768

typedef __attribute__((ext_vector_type(4))) float f32x4;
typedef __attribute__((ext_vector_type(8))) short bf16x8s;
typedef __attribute__((ext_vector_type(4))) unsigned short u16x4;
typedef __attribute__((ext_vector_type(8))) unsigned short u16x8;
typedef __attribute__((ext_vector_type(4))) unsigned int u32x4;

__device__ __forceinline__ unsigned short f2bf(float f) {
  unsigned int u = __float_as_uint(f);
  u += 0x7FFFu + ((u >> 16) & 1u);   // RNE
  return (unsigned short)(u >> 16);
}
__device__ __forceinline__ float bf2f(unsigned short h) {
  return __uint_as_float(((unsigned int)h) << 16);
}
// HW packed f32->bf16 (RNE), 2 elements per instruction
__device__ __forceinline__ unsigned int cvtpk(float lo, float hi) {
  unsigned int r;
  asm("v_cvt_pk_bf16_f32 %0, %1, %2" : "=v"(r) : "v"(lo), "v"(hi));
  return r;
}
__device__ __forceinline__ void gload_lds16(const void* g, void* l) {
  __builtin_amdgcn_global_load_lds((const __attribute__((address_space(1))) void*)g,
                                   (__attribute__((address_space(3))) void*)l, 16, 0, 0);
}

// packed layout for a [R][K] bf16 tensor (R%16==0, K%32==0), KT=K/32:
// elem(r,k) = ((r>>4)*KT + (k>>5))*512 + ((k>>3)&3)*128 + (r&15)*8 + (k&7)

// ---------------- merged prep: pack_w + 2 transposes + pack_xyz2 ----------------
__device__ __forceinline__ void transpose_body(
    const float* __restrict__ in, unsigned short* __restrict__ out,
    int C, int S, int KT, int packed, int bx, int by, int bz, int t,
    float (*LT)[65]) {
  const int s0 = bx * 64, c0 = by * 64;
  const float* inb = in + (size_t)bz * C * S;
  const int cr = t >> 4, sq = t & 15;
  #pragma unroll
  for (int it = 0; it < 4; ++it) {
    int cc = cr + it * 16;
    float4 v = *reinterpret_cast<const float4*>(inb + (size_t)(c0 + cc) * S + s0 + sq * 4);
    LT[sq * 4 + 0][cc] = v.x; LT[sq * 4 + 1][cc] = v.y;
    LT[sq * 4 + 2][cc] = v.z; LT[sq * 4 + 3][cc] = v.w;
  }
  __syncthreads();
  const int sr = t >> 2, cq = t & 3;
  u16x8 o0v, o1v;
  #pragma unroll
  for (int k = 0; k < 8; ++k) o0v[k] = f2bf(LT[sr][cq * 16 + k]);
  #pragma unroll
  for (int k = 0; k < 8; ++k) o1v[k] = f2bf(LT[sr][cq * 16 + 8 + k]);
  if (packed) {
    size_t rg = (size_t)bz * S + s0 + sr;
    int c = c0 + cq * 16;
    size_t ad = ((rg >> 4) * KT + (c >> 5)) * 512 + ((c >> 3) & 3) * 128 + (rg & 15) * 8;
    *reinterpret_cast<u16x8*>(out + ad) = o0v;
    *reinterpret_cast<u16x8*>(out + ad + 128) = o1v;
  } else {
    unsigned short* op = out + ((size_t)bz * S + s0 + sr) * 256 + c0 + cq * 16;
    *reinterpret_cast<u16x8*>(op) = o0v;
    *reinterpret_cast<u16x8*>(op + 8) = o1v;
  }
}

__global__ __launch_bounds__(256) void prep_all(
    const float* __restrict__ points2, unsigned short* __restrict__ p2t,
    const float* __restrict__ points1, unsigned short* __restrict__ X1,
    const float* __restrict__ w1, const float* __restrict__ w2,
    const float* __restrict__ w3, unsigned short* __restrict__ o1,
    unsigned short* __restrict__ o2, unsigned short* __restrict__ o3,
    const float* __restrict__ xyz2, float4* __restrict__ sptg) {
  __shared__ float LT[64][65];
  const int bid = blockIdx.x, t = threadIdx.x;
  if (bid < 512) {
    // points2 [256][2048] -> p2t linear [s][256]; grid (32,4,4)
    int x = bid & 31, y = (bid >> 5) & 3, z = bid >> 7;
    transpose_body(points2, p2t, 256, SPTS, 0, 0, x, y, z, t, LT);
  } else if (bid < 1536) {
    // points1 [128][8192] -> X1 packed (K=384 cols 0..127); grid (128,2,4)
    int b2 = bid - 512;
    int x = b2 & 127, y = (b2 >> 7) & 1, z = b2 >> 8;
    transpose_body(points1, X1, 128, NPTS, 12, 1, x, y, z, t, LT);
  } else if (bid < 1648) {
    // pack_w
    int gid = (bid - 1536) * 256 + t;
    const float* src;
    unsigned short* dst;
    int K, cl;
    if (gid < 12288) { src = w1; dst = o1; K = 384; cl = gid; }
    else if (gid < 20480) { src = w2; dst = o2; K = 256; cl = gid - 12288; }
    else if (gid < 28672) { src = w3; dst = o3; K = 256; cl = gid - 20480; }
    else return;
    int cpo = K >> 3;
    int o = cl / cpo, k0 = (cl - o * cpo) * 8;
    float4 a = *reinterpret_cast<const float4*>(src + (size_t)o * K + k0);
    float4 b = *reinterpret_cast<const float4*>(src + (size_t)o * K + k0 + 4);
    u16x8 v;
    v[0] = f2bf(a.x); v[1] = f2bf(a.y); v[2] = f2bf(a.z); v[3] = f2bf(a.w);
    v[4] = f2bf(b.x); v[5] = f2bf(b.y); v[6] = f2bf(b.z); v[7] = f2bf(b.w);
    int KT = K >> 5;
    size_t ad = ((size_t)(o >> 4) * KT + (k0 >> 5)) * 512 + ((k0 >> 3) & 3) * 128 + (o & 15) * 8;
    *reinterpret_cast<u16x8*>(dst + ad) = v;
  } else {
    // pack_xyz2
    int gid = (bid - 1648) * 256 + t;
    const float* p = xyz2 + (size_t)gid * 3;
    float x = p[0], y = p[1], z = p[2];
    float b2 = __fadd_rn(__fadd_rn(__fmul_rn(x, x), __fmul_rn(y, y)), __fmul_rn(z, z));
    sptg[gid] = make_float4(x, y, z, b2);
  }
}

// ---------------- KNN (k=3) + fused IDW gather ----------------
#define CSINS(q, dd, s)                                                    \
  do {                                                                     \
    float tt = dd; int ti = s;                                             \
    bool c0 = tt < d0[q];                                                  \
    float h = c0 ? d0[q] : tt; int hi_ = c0 ? i0[q] : ti;                  \
    d0[q] = c0 ? tt : d0[q];   i0[q] = c0 ? ti : i0[q];                    \
    tt = h; ti = hi_;                                                      \
    bool c1 = tt < d1[q];                                                  \
    h = c1 ? d1[q] : tt; hi_ = c1 ? i1[q] : ti;                            \
    d1[q] = c1 ? tt : d1[q];   i1[q] = c1 ? ti : i1[q];                    \
    tt = h; ti = hi_;                                                      \
    bool c2 = tt < d2[q];                                                  \
    d2[q] = c2 ? tt : d2[q];   i2[q] = c2 ? ti : i2[q];                    \
  } while (0)

#define INSK(x)                                                            \
  do {                                                                     \
    bool c0 = (x) < k0, c1 = (x) < k1, c2 = (x) < k2;                      \
    unsigned long long nk0 = c0 ? (x) : k0;                                \
    unsigned long long nk1 = c0 ? k0 : (c1 ? (x) : k1);                    \
    unsigned long long nk2 = c1 ? k1 : (c2 ? (x) : k2);                    \
    k0 = nk0; k1 = nk1; k2 = nk2;                                          \
  } while (0)

__device__ __forceinline__ unsigned long long packdi(float d, int i) {
  unsigned int b = __float_as_uint(d);
  unsigned int u = b ^ ((unsigned int)((int)b >> 31) | 0x80000000u);
  return ((unsigned long long)u << 32) | (unsigned int)i;
}
__device__ __forceinline__ float unpackd(unsigned long long k) {
  unsigned int u = (unsigned int)(k >> 32);
  unsigned int b = u ^ ((u & 0x80000000u) ? 0x80000000u : 0xFFFFFFFFu);
  return __uint_as_float(b);
}

__global__ __launch_bounds__(256) void knn_gather(
    const float* __restrict__ xyz1, const float4* __restrict__ sptg,
    const unsigned short* __restrict__ p2t, unsigned short* __restrict__ X1) {
  const int b = blockIdx.y, t = threadIdx.x;
  const int wave = t >> 6, lane = t & 63;
  const int nb = blockIdx.x * 16 + wave * 4;
  const float4* sp = sptg + (size_t)b * SPTS;

  float qx[4], qy[4], qz[4], a2[4];
  float d0[4], d1[4], d2[4];
  int i0[4], i1[4], i2[4];
  #pragma unroll
  for (int q = 0; q < 4; ++q) {
    const float* qp = xyz1 + ((size_t)b * NPTS + nb + q) * 3;
    qx[q] = qp[0]; qy[q] = qp[1]; qz[q] = qp[2];
    a2[q] = __fadd_rn(__fadd_rn(__fmul_rn(qx[q], qx[q]), __fmul_rn(qy[q], qy[q])),
                      __fmul_rn(qz[q], qz[q]));
    d0[q] = 1e30f; d1[q] = 1e30f; d2[q] = 1e30f;
    i0[q] = 0; i1[q] = 0; i2[q] = 0;
  }

  #pragma unroll 2
  for (int it = 0; it < SPTS / 128; ++it) {
    int sA = it * 128 + lane;
    int sB = sA + 64;
    float4 pA = sp[sA];
    float4 pB = sp[sB];
    #pragma unroll
    for (int q = 0; q < 4; ++q) {
      float dotA = __fadd_rn(__fadd_rn(__fmul_rn(qx[q], pA.x), __fmul_rn(qy[q], pA.y)),
                             __fmul_rn(qz[q], pA.z));
      float dA = __fsub_rn(__fadd_rn(a2[q], pA.w), __fmul_rn(2.0f, dotA));
      float dotB = __fadd_rn(__fadd_rn(__fmul_rn(qx[q], pB.x), __fmul_rn(qy[q], pB.y)),
                             __fmul_rn(qz[q], pB.z));
      float dB = __fsub_rn(__fadd_rn(a2[q], pB.w), __fmul_rn(2.0f, dotB));
      CSINS(q, dA, sA);
      CSINS(q, dB, sB);
    }
  }

  #pragma unroll
  for (int q = 0; q < 4; ++q) {
    unsigned long long k0 = packdi(d0[q], i0[q]);
    unsigned long long k1 = packdi(d1[q], i1[q]);
    unsigned long long k2 = packdi(d2[q], i2[q]);
    #pragma unroll
    for (int m = 1; m < 64; m <<= 1) {
      unsigned long long x0 = __shfl_xor(k0, m);
      unsigned long long x1 = __shfl_xor(k1, m);
      unsigned long long x2 = __shfl_xor(k2, m);
      INSK(x0); INSK(x1); INSK(x2);
    }
    int j0 = (int)(k0 & 0xFFFFFFFFu);
    int j1 = (int)(k1 & 0xFFFFFFFFu);
    int j2 = (int)(k2 & 0xFFFFFFFFu);
    float r0 = 1.0f / __fadd_rn(unpackd(k0), 1e-8f);
    float r1 = 1.0f / __fadd_rn(unpackd(k1), 1e-8f);
    float r2 = 1.0f / __fadd_rn(unpackd(k2), 1e-8f);
    float rs = __fadd_rn(__fadd_rn(r0, r1), r2);
    float w0 = r0 / rs, w1 = r1 / rs, w2 = r2 / rs;

    const unsigned short* rw0 = p2t + ((size_t)b * SPTS + j0) * 256 + lane * 4;
    const unsigned short* rw1 = p2t + ((size_t)b * SPTS + j1) * 256 + lane * 4;
    const unsigned short* rw2 = p2t + ((size_t)b * SPTS + j2) * 256 + lane * 4;
    u16x4 v0 = *reinterpret_cast<const u16x4*>(rw0);
    u16x4 v1 = *reinterpret_cast<const u16x4*>(rw1);
    u16x4 v2 = *reinterpret_cast<const u16x4*>(rw2);
    u16x4 o;
    #pragma unroll
    for (int e = 0; e < 4; ++e) {
      float f = w0 * bf2f(v0[e]) + w1 * bf2f(v1[e]) + w2 * bf2f(v2[e]);
      o[e] = f2bf(f);
    }
    size_t rg = (size_t)b * NPTS + nb + q;
    int ca = 128 + lane * 4;
    size_t ad = (rg >> 4) * 12 * 512 + (rg & 15) * 8 + (size_t)(ca >> 5) * 512 +
                ((ca >> 3) & 3) * 128 + (ca & 7);
    *reinterpret_cast<u16x4*>(X1 + ad) = o;
  }
}

// ---------------- packed bf16 MFMA GEMM v8 (= v7 with cvt_pk conversions) ----
template <int K, bool BNIN>
__global__ __launch_bounds__(256) void gemm_packed(
    const unsigned short* __restrict__ Wp, const unsigned short* __restrict__ Xp,
    const float* __restrict__ ssp, const float* __restrict__ bias,
    unsigned short* __restrict__ Z, float* __restrict__ part) {
  constexpr int KT = K / 32;
  __shared__ unsigned short Ws[4 * KT * 512];
  const int t = threadIdx.x, wave = t >> 6, lane = t & 63;
  const int lr = lane & 15, hi4 = lane >> 4;
  const int id = blockIdx.x;
  const int wg = (id & 7) * 64 + (id >> 3);
  const int br = wg >> 2;
  const int cb = wg & 3;

  // 3-deep X prefetch (kt=0,1,2), issued BEFORE the W-stage barrier
  const unsigned short* Xb = Xp + ((size_t)(br * 16 + wave * 4) * KT) * 512 + lane * 8;
  u16x8 xp[3][4];
  #pragma unroll
  for (int d = 0; d < 3; ++d)
    #pragma unroll
    for (int rr = 0; rr < 4; ++rr)
      xp[d][rr] = *reinterpret_cast<const u16x8*>(Xb + ((size_t)rr * KT + d) * 512);

  const unsigned short* Wsrc = Wp + (size_t)cb * 4 * KT * 512;
  constexpr int WCH = 4 * KT * 512 / 8;
  #pragma unroll
  for (int i = 0; i < WCH / 256; ++i)
    gload_lds16(Wsrc + (size_t)(t + i * 256) * 8, Ws + (t + i * 256) * 8);
  __syncthreads();

  f32x4 acc[4][4];
  #pragma unroll
  for (int rr = 0; rr < 4; ++rr)
    #pragma unroll
    for (int ot = 0; ot < 4; ++ot) acc[rr][ot] = (f32x4)0.f;

  #pragma unroll
  for (int kt = 0; kt < KT; ++kt) {
    const int slot = kt % 3;
    u16x8 xc[4];
    #pragma unroll
    for (int rr = 0; rr < 4; ++rr) xc[rr] = xp[slot][rr];
    if (kt + 3 < KT) {
      #pragma unroll
      for (int rr = 0; rr < 4; ++rr)
        xp[slot][rr] = *reinterpret_cast<const u16x8*>(Xb + ((size_t)rr * KT + kt + 3) * 512);
    }
    bf16x8s xf[4];
    if constexpr (BNIN) {
      const int cbase = kt * 32 + hi4 * 8;
      f32x4 s0 = *reinterpret_cast<const f32x4*>(ssp + cbase);
      f32x4 s1 = *reinterpret_cast<const f32x4*>(ssp + cbase + 4);
      f32x4 h0 = *reinterpret_cast<const f32x4*>(ssp + 256 + cbase);
      f32x4 h1 = *reinterpret_cast<const f32x4*>(ssp + 256 + cbase + 4);
      #pragma unroll
      for (int rr = 0; rr < 4; ++rr) {
        float y0 = fmaxf(s0[0] * bf2f(xc[rr][0]) + h0[0], 0.f);
        float y1 = fmaxf(s0[1] * bf2f(xc[rr][1]) + h0[1], 0.f);
        float y2 = fmaxf(s0[2] * bf2f(xc[rr][2]) + h0[2], 0.f);
        float y3 = fmaxf(s0[3] * bf2f(xc[rr][3]) + h0[3], 0.f);
        float y4 = fmaxf(s1[0] * bf2f(xc[rr][4]) + h1[0], 0.f);
        float y5 = fmaxf(s1[1] * bf2f(xc[rr][5]) + h1[1], 0.f);
        float y6 = fmaxf(s1[2] * bf2f(xc[rr][6]) + h1[2], 0.f);
        float y7 = fmaxf(s1[3] * bf2f(xc[rr][7]) + h1[3], 0.f);
        u32x4 xw = {cvtpk(y0, y1), cvtpk(y2, y3), cvtpk(y4, y5), cvtpk(y6, y7)};
        xf[rr] = *reinterpret_cast<bf16x8s*>(&xw);
      }
    } else {
      #pragma unroll
      for (int rr = 0; rr < 4; ++rr)
        xf[rr] = *reinterpret_cast<bf16x8s*>(&xc[rr]);
    }
    bf16x8s wf[4];
    #pragma unroll
    for (int ot = 0; ot < 4; ++ot)
      wf[ot] = *reinterpret_cast<const bf16x8s*>(Ws + (size_t)(ot * KT + kt) * 512 + lane * 8);
    #pragma unroll
    for (int rr = 0; rr < 4; ++rr)
      #pragma unroll
      for (int ot = 0; ot < 4; ++ot)
        acc[rr][ot] =
            __builtin_amdgcn_mfma_f32_16x16x32_bf16(wf[ot], xf[rr], acc[rr][ot], 0, 0, 0);
  }

  const size_t pbase = (size_t)(br * 4 + wave) * 512;
  #pragma unroll
  for (int ot = 0; ot < 4; ++ot) {
    const int o_c = cb * 64 + ot * 16 + hi4 * 4;
    f32x4 bv = *reinterpret_cast<const f32x4*>(bias + o_c);
    const int kto = o_c >> 5, hb = (o_c >> 3) & 3, e0 = o_c & 7;
    float sm[4] = {0.f, 0.f, 0.f, 0.f}, sq[4] = {0.f, 0.f, 0.f, 0.f};
    #pragma unroll
    for (int rr = 0; rr < 4; ++rr) {
      f32x4 v = acc[rr][ot] + bv;
      #pragma unroll
      for (int e = 0; e < 4; ++e) {
        sm[e] += v[e];
        sq[e] += v[e] * v[e];
      }
      unsigned int o01 = cvtpk(v[0], v[1]);
      unsigned int o23 = cvtpk(v[2], v[3]);
      size_t rtg = (size_t)br * 16 + wave * 4 + rr;
      size_t ad = (rtg * 8 + kto) * 512 + hb * 128 + lr * 8 + e0;
      *reinterpret_cast<uint2*>(Z + ad) = make_uint2(o01, o23);
    }
    #pragma unroll
    for (int m = 8; m >= 1; m >>= 1) {
      #pragma unroll
      for (int e = 0; e < 4; ++e) {
        sm[e] += __shfl_xor(sm[e], m);
        sq[e] += __shfl_xor(sq[e], m);
      }
    }
    if (lr == 0) {
      f32x4 vs = {sm[0], sm[1], sm[2], sm[3]};
      f32x4 vq = {sq[0], sq[1], sq[2], sq[3]};
      *reinterpret_cast<f32x4*>(part + pbase + o_c) = vs;
      *reinterpret_cast<f32x4*>(part + pbase + 256 + o_c) = vq;
    }
  }
}

// ---------------- reduce partials (512 strips) -> per-channel scale/shift ----------------
__global__ __launch_bounds__(256) void reduce_stats(
    const float* __restrict__ part, const float* __restrict__ gamma,
    const float* __restrict__ beta, float* __restrict__ ss) {
  __shared__ float red[8][64];
  const int t = threadIdx.x;
  const int strip = t >> 5, ch = t & 31;
  const int c = blockIdx.x * 32 + ch;
  float sm = 0.f, sq = 0.f;
  for (int i = strip; i < 512; i += 8) {
    sm += part[(size_t)i * 512 + c];
    sq += part[(size_t)i * 512 + 256 + c];
  }
  red[strip][ch * 2] = sm;
  red[strip][ch * 2 + 1] = sq;
  __syncthreads();
  if (strip == 0) {
    #pragma unroll
    for (int k = 1; k < 8; ++k) {
      sm += red[k][ch * 2];
      sq += red[k][ch * 2 + 1];
    }
    const float inv = 1.0f / (float)TOTAL_ROWS;
    float mean = sm * inv;
    float var = sq * inv - mean * mean;
    float sc = gamma[c] * rsqrtf(var + 1e-5f);
    ss[c] = sc;
    ss[256 + c] = beta[c] - mean * sc;
  }
}

// ---------------- final: BN3 + residual(BN1 of Z1) + ReLU + transpose out ----------------
__global__ __launch_bounds__(256) void bn_res_out(
    const unsigned short* __restrict__ Z, const unsigned short* __restrict__ Zres,
    const float* __restrict__ ss_res, const float* __restrict__ ss_out,
    float* __restrict__ out) {
  __shared__ float LT[64][65];
  const int b = blockIdx.z, n0 = blockIdx.x * 64, o0 = blockIdx.y * 64;
  const int t = threadIdx.x;
  #pragma unroll
  for (int i = 0; i < 2; ++i) {
    int cid = t + i * 256;
    int r = cid & 15, hi = (cid >> 4) & 3, ktl = (cid >> 6) & 1, rtl = cid >> 7;
    size_t rt = (size_t)b * (NPTS / 16) + (n0 >> 4) + rtl;
    int kt = (o0 >> 5) + ktl;
    size_t ad = (rt * 8 + kt) * 512 + hi * 128 + r * 8;
    u16x8 z = *reinterpret_cast<const u16x8*>(Z + ad);
    u16x8 x = *reinterpret_cast<const u16x8*>(Zres + ad);
    int ob = o0 + ktl * 32 + hi * 8;
    #pragma unroll
    for (int e = 0; e < 8; ++e) {
      int c = ob + e;
      float xv = fmaxf(ss_res[c] * bf2f(x[e]) + ss_res[256 + c], 0.f);
      LT[ktl * 32 + hi * 8 + e][rtl * 16 + r] =
          fmaxf(ss_out[c] * bf2f(z[e]) + ss_out[256 + c] + xv, 0.f);
    }
  }
  __syncthreads();
  const int orow = t >> 2, nq = t & 3;
  float* op = out + ((size_t)b * CO + o0 + orow) * NPTS + n0 + nq * 16;
  #pragma unroll
  for (int j = 0; j < 4; ++j) {
    float4 v = make_float4(LT[orow][nq * 16 + j * 4 + 0], LT[orow][nq * 16 + j * 4 + 1],
                           LT[orow][nq * 16 + j * 4 + 2], LT[orow][nq * 16 + j * 4 + 3]);
    *reinterpret_cast<float4*>(op + j * 4) = v;
  }
}

extern "C" void kernel_launch(void* const* d_in, const int* in_sizes, int n_in,
                              void* d_out, int out_size, void* d_ws, size_t ws_size,
                              hipStream_t stream) {
  const float* xyz1    = (const float*)d_in[0];
  const float* xyz2    = (const float*)d_in[1];
  const float* points1 = (const float*)d_in[2];
  const float* points2 = (const float*)d_in[3];
  const float* fuse_w  = (const float*)d_in[4];
  const float* fuse_b  = (const float*)d_in[5];
  const float* fuse_g  = (const float*)d_in[6];
  const float* fuse_be = (const float*)d_in[7];
  const float* e1_w    = (const float*)d_in[8];
  const float* e1_b    = (const float*)d_in[9];
  const float* e1_g    = (const float*)d_in[10];
  const float* e1_be   = (const float*)d_in[11];
  const float* e2_w    = (const float*)d_in[12];
  const float* e2_b    = (const float*)d_in[13];
  const float* e2_g    = (const float*)d_in[14];
  const float* e2_be   = (const float*)d_in[15];
  float* out = (float*)d_out;

  char* w = (char*)d_ws;
  auto carve = [&](size_t bytes) {
    char* p = w;
    w += (bytes + 255) & ~(size_t)255;
    return p;
  };
  unsigned short* Wb1 = (unsigned short*)carve(98304 * 2);
  unsigned short* Wb2 = (unsigned short*)carve(65536 * 2);
  unsigned short* Wb3 = (unsigned short*)carve(65536 * 2);
  unsigned short* p2t = (unsigned short*)carve((size_t)BATCH * SPTS * 256 * 2);
  float4* sptg        = (float4*)carve((size_t)BATCH * SPTS * 16);
  unsigned short* X1  = (unsigned short*)carve((size_t)TOTAL_ROWS * 384 * 2);
  unsigned short* Z1  = (unsigned short*)carve((size_t)TOTAL_ROWS * 256 * 2);
  unsigned short* Z2  = (unsigned short*)carve((size_t)TOTAL_ROWS * 256 * 2);
  unsigned short* Z3  = (unsigned short*)carve((size_t)TOTAL_ROWS * 256 * 2);
  float* part         = (float*)carve((size_t)512 * 512 * 4);
  float* ss           = (float*)carve(3 * 512 * 4);

  // merged prep: transposes + weight pack + xyz2 pack (1680 blocks)
  prep_all<<<dim3(1680), 256, 0, stream>>>(points2, p2t, points1, X1,
                                           fuse_w, e1_w, e2_w, Wb1, Wb2, Wb3,
                                           xyz2, sptg);

  // KNN + fused IDW gather -> X1 packed (K=384, cols 128..383)
  knn_gather<<<dim3(NPTS / 16, BATCH), 256, 0, stream>>>(xyz1, sptg, p2t, X1);

  // stage 1: fuse (K=384), raw input
  gemm_packed<384, false><<<dim3(512), 256, 0, stream>>>(Wb1, X1, nullptr, fuse_b, Z1, part);
  reduce_stats<<<dim3(8), 256, 0, stream>>>(part, fuse_g, fuse_be, ss);

  // stage 2: net1 (K=256), BN1+ReLU fused into X path
  gemm_packed<256, true><<<dim3(512), 256, 0, stream>>>(Wb2, Z1, ss, e1_b, Z2, part);
  reduce_stats<<<dim3(8), 256, 0, stream>>>(part, e1_g, e1_be, ss + 512);

  // stage 3: net2 (K=256), BN2+ReLU fused into X path
  gemm_packed<256, true><<<dim3(512), 256, 0, stream>>>(Wb3, Z2, ss + 512, e2_b, Z3, part);
  reduce_stats<<<dim3(8), 256, 0, stream>>>(part, e2_g, e2_be, ss + 1024);

  // final: BN3(Z3) + residual BN1(Z1) + ReLU + transpose to out
  bn_res_out<<<dim3(NPTS / 64, 4, BATCH), 256, 0, stream>>>(Z3, Z1, ss, ss + 1024, out);
}

// Round 15
// 144.991 us; speedup vs baseline: 1.7758x; 1.3102x over previous
//
#include <hip/hip_runtime.h>

#define NPTS 8192
#define SPTS 2048
#define BATCH 4
#define CO 256
#define TOTAL_ROWS (BATCH * NPTS)  // 32768

typedef __attribute__((ext_vector_type(4))) float f32x4;
typedef __attribute__((ext_vector_type(8))) short bf16x8s;
typedef __attribute__((ext_vector_type(4))) unsigned short u16x4;
typedef __attribute__((ext_vector_type(8))) unsigned short u16x8;
typedef __attribute__((ext_vector_type(4))) unsigned int u32x4;

__device__ __forceinline__ unsigned short f2bf(float f) {
  unsigned int u = __float_as_uint(f);
  u += 0x7FFFu + ((u >> 16) & 1u);   // RNE
  return (unsigned short)(u >> 16);
}
__device__ __forceinline__ float bf2f(unsigned short h) {
  return __uint_as_float(((unsigned int)h) << 16);
}
// HW packed f32->bf16 (RNE), 2 elements per instruction
__device__ __forceinline__ unsigned int cvtpk(float lo, float hi) {
  unsigned int r;
  asm("v_cvt_pk_bf16_f32 %0, %1, %2" : "=v"(r) : "v"(lo), "v"(hi));
  return r;
}
__device__ __forceinline__ void gload_lds16(const void* g, void* l) {
  __builtin_amdgcn_global_load_lds((const __attribute__((address_space(1))) void*)g,
                                   (__attribute__((address_space(3))) void*)l, 16, 0, 0);
}

// packed layout for a [R][K] bf16 tensor (R%16==0, K%32==0), KT=K/32:
// elem(r,k) = ((r>>4)*KT + (k>>5))*512 + ((k>>3)&3)*128 + (r&15)*8 + (k&7)

// ---------------- merged prep: pack_w + 2 transposes + pack_xyz2 ----------------
__device__ __forceinline__ void transpose_body(
    const float* __restrict__ in, unsigned short* __restrict__ out,
    int C, int S, int KT, int packed, int bx, int by, int bz, int t,
    float (*LT)[65]) {
  const int s0 = bx * 64, c0 = by * 64;
  const float* inb = in + (size_t)bz * C * S;
  const int cr = t >> 4, sq = t & 15;
  #pragma unroll
  for (int it = 0; it < 4; ++it) {
    int cc = cr + it * 16;
    float4 v = *reinterpret_cast<const float4*>(inb + (size_t)(c0 + cc) * S + s0 + sq * 4);
    LT[sq * 4 + 0][cc] = v.x; LT[sq * 4 + 1][cc] = v.y;
    LT[sq * 4 + 2][cc] = v.z; LT[sq * 4 + 3][cc] = v.w;
  }
  __syncthreads();
  const int sr = t >> 2, cq = t & 3;
  u16x8 o0v, o1v;
  #pragma unroll
  for (int k = 0; k < 8; ++k) o0v[k] = f2bf(LT[sr][cq * 16 + k]);
  #pragma unroll
  for (int k = 0; k < 8; ++k) o1v[k] = f2bf(LT[sr][cq * 16 + 8 + k]);
  if (packed) {
    size_t rg = (size_t)bz * S + s0 + sr;
    int c = c0 + cq * 16;
    size_t ad = ((rg >> 4) * KT + (c >> 5)) * 512 + ((c >> 3) & 3) * 128 + (rg & 15) * 8;
    *reinterpret_cast<u16x8*>(out + ad) = o0v;
    *reinterpret_cast<u16x8*>(out + ad + 128) = o1v;
  } else {
    unsigned short* op = out + ((size_t)bz * S + s0 + sr) * 256 + c0 + cq * 16;
    *reinterpret_cast<u16x8*>(op) = o0v;
    *reinterpret_cast<u16x8*>(op + 8) = o1v;
  }
}

__global__ __launch_bounds__(256) void prep_all(
    const float* __restrict__ points2, unsigned short* __restrict__ p2t,
    const float* __restrict__ points1, unsigned short* __restrict__ X1,
    const float* __restrict__ w1, const float* __restrict__ w2,
    const float* __restrict__ w3, unsigned short* __restrict__ o1,
    unsigned short* __restrict__ o2, unsigned short* __restrict__ o3,
    const float* __restrict__ xyz2, float4* __restrict__ sptg) {
  __shared__ float LT[64][65];
  const int bid = blockIdx.x, t = threadIdx.x;
  if (bid < 512) {
    int x = bid & 31, y = (bid >> 5) & 3, z = bid >> 7;
    transpose_body(points2, p2t, 256, SPTS, 0, 0, x, y, z, t, LT);
  } else if (bid < 1536) {
    int b2 = bid - 512;
    int x = b2 & 127, y = (b2 >> 7) & 1, z = b2 >> 8;
    transpose_body(points1, X1, 128, NPTS, 12, 1, x, y, z, t, LT);
  } else if (bid < 1648) {
    int gid = (bid - 1536) * 256 + t;
    const float* src;
    unsigned short* dst;
    int K, cl;
    if (gid < 12288) { src = w1; dst = o1; K = 384; cl = gid; }
    else if (gid < 20480) { src = w2; dst = o2; K = 256; cl = gid - 12288; }
    else if (gid < 28672) { src = w3; dst = o3; K = 256; cl = gid - 20480; }
    else return;
    int cpo = K >> 3;
    int o = cl / cpo, k0 = (cl - o * cpo) * 8;
    float4 a = *reinterpret_cast<const float4*>(src + (size_t)o * K + k0);
    float4 b = *reinterpret_cast<const float4*>(src + (size_t)o * K + k0 + 4);
    u16x8 v;
    v[0] = f2bf(a.x); v[1] = f2bf(a.y); v[2] = f2bf(a.z); v[3] = f2bf(a.w);
    v[4] = f2bf(b.x); v[5] = f2bf(b.y); v[6] = f2bf(b.z); v[7] = f2bf(b.w);
    int KT = K >> 5;
    size_t ad = ((size_t)(o >> 4) * KT + (k0 >> 5)) * 512 + ((k0 >> 3) & 3) * 128 + (o & 15) * 8;
    *reinterpret_cast<u16x8*>(dst + ad) = v;
  } else {
    int gid = (bid - 1648) * 256 + t;
    const float* p = xyz2 + (size_t)gid * 3;
    float x = p[0], y = p[1], z = p[2];
    float b2 = __fadd_rn(__fadd_rn(__fmul_rn(x, x), __fmul_rn(y, y)), __fmul_rn(z, z));
    sptg[gid] = make_float4(x, y, z, b2);
  }
}

// ---------------- KNN (k=3) + fused IDW gather ----------------
#define CSINS(q, dd, s)                                                    \
  do {                                                                     \
    float tt = dd; int ti = s;                                             \
    bool c0 = tt < d0[q];                                                  \
    float h = c0 ? d0[q] : tt; int hi_ = c0 ? i0[q] : ti;                  \
    d0[q] = c0 ? tt : d0[q];   i0[q] = c0 ? ti : i0[q];                    \
    tt = h; ti = hi_;                                                      \
    bool c1 = tt < d1[q];                                                  \
    h = c1 ? d1[q] : tt; hi_ = c1 ? i1[q] : ti;                            \
    d1[q] = c1 ? tt : d1[q];   i1[q] = c1 ? ti : i1[q];                    \
    tt = h; ti = hi_;                                                      \
    bool c2 = tt < d2[q];                                                  \
    d2[q] = c2 ? tt : d2[q];   i2[q] = c2 ? ti : i2[q];                    \
  } while (0)

#define INSK(x)                                                            \
  do {                                                                     \
    bool c0 = (x) < k0, c1 = (x) < k1, c2 = (x) < k2;                      \
    unsigned long long nk0 = c0 ? (x) : k0;                                \
    unsigned long long nk1 = c0 ? k0 : (c1 ? (x) : k1);                    \
    unsigned long long nk2 = c1 ? k1 : (c2 ? (x) : k2);                    \
    k0 = nk0; k1 = nk1; k2 = nk2;                                          \
  } while (0)

__device__ __forceinline__ unsigned long long packdi(float d, int i) {
  unsigned int b = __float_as_uint(d);
  unsigned int u = b ^ ((unsigned int)((int)b >> 31) | 0x80000000u);
  return ((unsigned long long)u << 32) | (unsigned int)i;
}
__device__ __forceinline__ float unpackd(unsigned long long k) {
  unsigned int u = (unsigned int)(k >> 32);
  unsigned int b = u ^ ((u & 0x80000000u) ? 0x80000000u : 0xFFFFFFFFu);
  return __uint_as_float(b);
}

__global__ __launch_bounds__(256) void knn_gather(
    const float* __restrict__ xyz1, const float4* __restrict__ sptg,
    const unsigned short* __restrict__ p2t, unsigned short* __restrict__ X1) {
  const int b = blockIdx.y, t = threadIdx.x;
  const int wave = t >> 6, lane = t & 63;
  const int nb = blockIdx.x * 16 + wave * 4;
  const float4* sp = sptg + (size_t)b * SPTS;

  float qx[4], qy[4], qz[4], a2[4];
  float d0[4], d1[4], d2[4];
  int i0[4], i1[4], i2[4];
  #pragma unroll
  for (int q = 0; q < 4; ++q) {
    const float* qp = xyz1 + ((size_t)b * NPTS + nb + q) * 3;
    qx[q] = qp[0]; qy[q] = qp[1]; qz[q] = qp[2];
    a2[q] = __fadd_rn(__fadd_rn(__fmul_rn(qx[q], qx[q]), __fmul_rn(qy[q], qy[q])),
                      __fmul_rn(qz[q], qz[q]));
    d0[q] = 1e30f; d1[q] = 1e30f; d2[q] = 1e30f;
    i0[q] = 0; i1[q] = 0; i2[q] = 0;
  }

  #pragma unroll 2
  for (int it = 0; it < SPTS / 128; ++it) {
    int sA = it * 128 + lane;
    int sB = sA + 64;
    float4 pA = sp[sA];
    float4 pB = sp[sB];
    #pragma unroll
    for (int q = 0; q < 4; ++q) {
      float dotA = __fadd_rn(__fadd_rn(__fmul_rn(qx[q], pA.x), __fmul_rn(qy[q], pA.y)),
                             __fmul_rn(qz[q], pA.z));
      float dA = __fsub_rn(__fadd_rn(a2[q], pA.w), __fmul_rn(2.0f, dotA));
      float dotB = __fadd_rn(__fadd_rn(__fmul_rn(qx[q], pB.x), __fmul_rn(qy[q], pB.y)),
                             __fmul_rn(qz[q], pB.z));
      float dB = __fsub_rn(__fadd_rn(a2[q], pB.w), __fmul_rn(2.0f, dotB));
      CSINS(q, dA, sA);
      CSINS(q, dB, sB);
    }
  }

  #pragma unroll
  for (int q = 0; q < 4; ++q) {
    unsigned long long k0 = packdi(d0[q], i0[q]);
    unsigned long long k1 = packdi(d1[q], i1[q]);
    unsigned long long k2 = packdi(d2[q], i2[q]);
    #pragma unroll
    for (int m = 1; m < 64; m <<= 1) {
      unsigned long long x0 = __shfl_xor(k0, m);
      unsigned long long x1 = __shfl_xor(k1, m);
      unsigned long long x2 = __shfl_xor(k2, m);
      INSK(x0); INSK(x1); INSK(x2);
    }
    int j0 = (int)(k0 & 0xFFFFFFFFu);
    int j1 = (int)(k1 & 0xFFFFFFFFu);
    int j2 = (int)(k2 & 0xFFFFFFFFu);
    float r0 = 1.0f / __fadd_rn(unpackd(k0), 1e-8f);
    float r1 = 1.0f / __fadd_rn(unpackd(k1), 1e-8f);
    float r2 = 1.0f / __fadd_rn(unpackd(k2), 1e-8f);
    float rs = __fadd_rn(__fadd_rn(r0, r1), r2);
    float w0 = r0 / rs, w1 = r1 / rs, w2 = r2 / rs;

    const unsigned short* rw0 = p2t + ((size_t)b * SPTS + j0) * 256 + lane * 4;
    const unsigned short* rw1 = p2t + ((size_t)b * SPTS + j1) * 256 + lane * 4;
    const unsigned short* rw2 = p2t + ((size_t)b * SPTS + j2) * 256 + lane * 4;
    u16x4 v0 = *reinterpret_cast<const u16x4*>(rw0);
    u16x4 v1 = *reinterpret_cast<const u16x4*>(rw1);
    u16x4 v2 = *reinterpret_cast<const u16x4*>(rw2);
    u16x4 o;
    #pragma unroll
    for (int e = 0; e < 4; ++e) {
      float f = w0 * bf2f(v0[e]) + w1 * bf2f(v1[e]) + w2 * bf2f(v2[e]);
      o[e] = f2bf(f);
    }
    size_t rg = (size_t)b * NPTS + nb + q;
    int ca = 128 + lane * 4;
    size_t ad = (rg >> 4) * 12 * 512 + (rg & 15) * 8 + (size_t)(ca >> 5) * 512 +
                ((ca >> 3) & 3) * 128 + (ca & 7);
    *reinterpret_cast<u16x4*>(X1 + ad) = o;
  }
}

// ---------------- packed bf16 MFMA GEMM v8 (frozen) ----------------
template <int K, bool BNIN>
__global__ __launch_bounds__(256) void gemm_packed(
    const unsigned short* __restrict__ Wp, const unsigned short* __restrict__ Xp,
    const float* __restrict__ ssp, const float* __restrict__ bias,
    unsigned short* __restrict__ Z, float* __restrict__ part) {
  constexpr int KT = K / 32;
  __shared__ unsigned short Ws[4 * KT * 512];
  const int t = threadIdx.x, wave = t >> 6, lane = t & 63;
  const int lr = lane & 15, hi4 = lane >> 4;
  const int id = blockIdx.x;
  const int wg = (id & 7) * 64 + (id >> 3);
  const int br = wg >> 2;
  const int cb = wg & 3;

  const unsigned short* Xb = Xp + ((size_t)(br * 16 + wave * 4) * KT) * 512 + lane * 8;
  u16x8 xp[3][4];
  #pragma unroll
  for (int d = 0; d < 3; ++d)
    #pragma unroll
    for (int rr = 0; rr < 4; ++rr)
      xp[d][rr] = *reinterpret_cast<const u16x8*>(Xb + ((size_t)rr * KT + d) * 512);

  const unsigned short* Wsrc = Wp + (size_t)cb * 4 * KT * 512;
  constexpr int WCH = 4 * KT * 512 / 8;
  #pragma unroll
  for (int i = 0; i < WCH / 256; ++i)
    gload_lds16(Wsrc + (size_t)(t + i * 256) * 8, Ws + (t + i * 256) * 8);
  __syncthreads();

  f32x4 acc[4][4];
  #pragma unroll
  for (int rr = 0; rr < 4; ++rr)
    #pragma unroll
    for (int ot = 0; ot < 4; ++ot) acc[rr][ot] = (f32x4)0.f;

  #pragma unroll
  for (int kt = 0; kt < KT; ++kt) {
    const int slot = kt % 3;
    u16x8 xc[4];
    #pragma unroll
    for (int rr = 0; rr < 4; ++rr) xc[rr] = xp[slot][rr];
    if (kt + 3 < KT) {
      #pragma unroll
      for (int rr = 0; rr < 4; ++rr)
        xp[slot][rr] = *reinterpret_cast<const u16x8*>(Xb + ((size_t)rr * KT + kt + 3) * 512);
    }
    bf16x8s xf[4];
    if constexpr (BNIN) {
      const int cbase = kt * 32 + hi4 * 8;
      f32x4 s0 = *reinterpret_cast<const f32x4*>(ssp + cbase);
      f32x4 s1 = *reinterpret_cast<const f32x4*>(ssp + cbase + 4);
      f32x4 h0 = *reinterpret_cast<const f32x4*>(ssp + 256 + cbase);
      f32x4 h1 = *reinterpret_cast<const f32x4*>(ssp + 256 + cbase + 4);
      #pragma unroll
      for (int rr = 0; rr < 4; ++rr) {
        float y0 = fmaxf(s0[0] * bf2f(xc[rr][0]) + h0[0], 0.f);
        float y1 = fmaxf(s0[1] * bf2f(xc[rr][1]) + h0[1], 0.f);
        float y2 = fmaxf(s0[2] * bf2f(xc[rr][2]) + h0[2], 0.f);
        float y3 = fmaxf(s0[3] * bf2f(xc[rr][3]) + h0[3], 0.f);
        float y4 = fmaxf(s1[0] * bf2f(xc[rr][4]) + h1[0], 0.f);
        float y5 = fmaxf(s1[1] * bf2f(xc[rr][5]) + h1[1], 0.f);
        float y6 = fmaxf(s1[2] * bf2f(xc[rr][6]) + h1[2], 0.f);
        float y7 = fmaxf(s1[3] * bf2f(xc[rr][7]) + h1[3], 0.f);
        u32x4 xw = {cvtpk(y0, y1), cvtpk(y2, y3), cvtpk(y4, y5), cvtpk(y6, y7)};
        xf[rr] = *reinterpret_cast<bf16x8s*>(&xw);
      }
    } else {
      #pragma unroll
      for (int rr = 0; rr < 4; ++rr)
        xf[rr] = *reinterpret_cast<bf16x8s*>(&xc[rr]);
    }
    bf16x8s wf[4];
    #pragma unroll
    for (int ot = 0; ot < 4; ++ot)
      wf[ot] = *reinterpret_cast<const bf16x8s*>(Ws + (size_t)(ot * KT + kt) * 512 + lane * 8);
    #pragma unroll
    for (int rr = 0; rr < 4; ++rr)
      #pragma unroll
      for (int ot = 0; ot < 4; ++ot)
        acc[rr][ot] =
            __builtin_amdgcn_mfma_f32_16x16x32_bf16(wf[ot], xf[rr], acc[rr][ot], 0, 0, 0);
  }

  const size_t pbase = (size_t)(br * 4 + wave) * 512;
  #pragma unroll
  for (int ot = 0; ot < 4; ++ot) {
    const int o_c = cb * 64 + ot * 16 + hi4 * 4;
    f32x4 bv = *reinterpret_cast<const f32x4*>(bias + o_c);
    const int kto = o_c >> 5, hb = (o_c >> 3) & 3, e0 = o_c & 7;
    float sm[4] = {0.f, 0.f, 0.f, 0.f}, sq[4] = {0.f, 0.f, 0.f, 0.f};
    #pragma unroll
    for (int rr = 0; rr < 4; ++rr) {
      f32x4 v = acc[rr][ot] + bv;
      #pragma unroll
      for (int e = 0; e < 4; ++e) {
        sm[e] += v[e];
        sq[e] += v[e] * v[e];
      }
      unsigned int o01 = cvtpk(v[0], v[1]);
      unsigned int o23 = cvtpk(v[2], v[3]);
      size_t rtg = (size_t)br * 16 + wave * 4 + rr;
      size_t ad = (rtg * 8 + kto) * 512 + hb * 128 + lr * 8 + e0;
      *reinterpret_cast<uint2*>(Z + ad) = make_uint2(o01, o23);
    }
    #pragma unroll
    for (int m = 8; m >= 1; m >>= 1) {
      #pragma unroll
      for (int e = 0; e < 4; ++e) {
        sm[e] += __shfl_xor(sm[e], m);
        sq[e] += __shfl_xor(sq[e], m);
      }
    }
    if (lr == 0) {
      f32x4 vs = {sm[0], sm[1], sm[2], sm[3]};
      f32x4 vq = {sq[0], sq[1], sq[2], sq[3]};
      *reinterpret_cast<f32x4*>(part + pbase + o_c) = vs;
      *reinterpret_cast<f32x4*>(part + pbase + 256 + o_c) = vq;
    }
  }
}

// ---------------- reduce partials v2: grid 64, short parallel chains ----------------
// part: 512 strips x 512 cols (cols 0..255 = sums, 256..511 = sumsq).
// block b handles channels b*4..b*4+3 (sum cols) + their sq cols.
__global__ __launch_bounds__(256) void reduce_stats(
    const float* __restrict__ part, const float* __restrict__ gamma,
    const float* __restrict__ beta, float* __restrict__ ss) {
  __shared__ float red[32][8];
  const int t = threadIdx.x;
  const int sg = t >> 3, co = t & 7;
  const int c = (co < 4) ? (blockIdx.x * 4 + co) : (256 + blockIdx.x * 4 + (co - 4));
  float sm = 0.f;
  #pragma unroll
  for (int k = 0; k < 16; ++k)
    sm += part[(size_t)(sg + 32 * k) * 512 + c];
  red[sg][co] = sm;
  __syncthreads();
  if (t < 8) {
    float s = 0.f;
    #pragma unroll
    for (int g = 0; g < 32; ++g) s += red[g][t];
    red[0][t] = s;
  }
  __syncthreads();
  if (t < 4) {
    int ch = blockIdx.x * 4 + t;
    const float inv = 1.0f / (float)TOTAL_ROWS;
    float mean = red[0][t] * inv;
    float var = red[0][t + 4] * inv - mean * mean;
    float sc = gamma[ch] * rsqrtf(var + 1e-5f);
    ss[ch] = sc;
    ss[256 + ch] = beta[ch] - mean * sc;
  }
}

// ---------------- final: BN3 + residual(BN1 of Z1) + ReLU + transpose out ----------------
__global__ __launch_bounds__(256) void bn_res_out(
    const unsigned short* __restrict__ Z, const unsigned short* __restrict__ Zres,
    const float* __restrict__ ss_res, const float* __restrict__ ss_out,
    float* __restrict__ out) {
  __shared__ float LT[64][65];
  const int b = blockIdx.z, n0 = blockIdx.x * 64, o0 = blockIdx.y * 64;
  const int t = threadIdx.x;
  #pragma unroll
  for (int i = 0; i < 2; ++i) {
    int cid = t + i * 256;
    int r = cid & 15, hi = (cid >> 4) & 3, ktl = (cid >> 6) & 1, rtl = cid >> 7;
    size_t rt = (size_t)b * (NPTS / 16) + (n0 >> 4) + rtl;
    int kt = (o0 >> 5) + ktl;
    size_t ad = (rt * 8 + kt) * 512 + hi * 128 + r * 8;
    u16x8 z = *reinterpret_cast<const u16x8*>(Z + ad);
    u16x8 x = *reinterpret_cast<const u16x8*>(Zres + ad);
    int ob = o0 + ktl * 32 + hi * 8;
    #pragma unroll
    for (int e = 0; e < 8; ++e) {
      int c = ob + e;
      float xv = fmaxf(ss_res[c] * bf2f(x[e]) + ss_res[256 + c], 0.f);
      LT[ktl * 32 + hi * 8 + e][rtl * 16 + r] =
          fmaxf(ss_out[c] * bf2f(z[e]) + ss_out[256 + c] + xv, 0.f);
    }
  }
  __syncthreads();
  const int orow = t >> 2, nq = t & 3;
  float* op = out + ((size_t)b * CO + o0 + orow) * NPTS + n0 + nq * 16;
  #pragma unroll
  for (int j = 0; j < 4; ++j) {
    float4 v = make_float4(LT[orow][nq * 16 + j * 4 + 0], LT[orow][nq * 16 + j * 4 + 1],
                           LT[orow][nq * 16 + j * 4 + 2], LT[orow][nq * 16 + j * 4 + 3]);
    *reinterpret_cast<float4*>(op + j * 4) = v;
  }
}

extern "C" void kernel_launch(void* const* d_in, const int* in_sizes, int n_in,
                              void* d_out, int out_size, void* d_ws, size_t ws_size,
                              hipStream_t stream) {
  const float* xyz1    = (const float*)d_in[0];
  const float* xyz2    = (const float*)d_in[1];
  const float* points1 = (const float*)d_in[2];
  const float* points2 = (const float*)d_in[3];
  const float* fuse_w  = (const float*)d_in[4];
  const float* fuse_b  = (const float*)d_in[5];
  const float* fuse_g  = (const float*)d_in[6];
  const float* fuse_be = (const float*)d_in[7];
  const float* e1_w    = (const float*)d_in[8];
  const float* e1_b    = (const float*)d_in[9];
  const float* e1_g    = (const float*)d_in[10];
  const float* e1_be   = (const float*)d_in[11];
  const float* e2_w    = (const float*)d_in[12];
  const float* e2_b    = (const float*)d_in[13];
  const float* e2_g    = (const float*)d_in[14];
  const float* e2_be   = (const float*)d_in[15];
  float* out = (float*)d_out;

  char* w = (char*)d_ws;
  auto carve = [&](size_t bytes) {
    char* p = w;
    w += (bytes + 255) & ~(size_t)255;
    return p;
  };
  unsigned short* Wb1 = (unsigned short*)carve(98304 * 2);
  unsigned short* Wb2 = (unsigned short*)carve(65536 * 2);
  unsigned short* Wb3 = (unsigned short*)carve(65536 * 2);
  unsigned short* p2t = (unsigned short*)carve((size_t)BATCH * SPTS * 256 * 2);
  float4* sptg        = (float4*)carve((size_t)BATCH * SPTS * 16);
  unsigned short* X1  = (unsigned short*)carve((size_t)TOTAL_ROWS * 384 * 2);
  unsigned short* Z1  = (unsigned short*)carve((size_t)TOTAL_ROWS * 256 * 2);
  unsigned short* Z2  = (unsigned short*)carve((size_t)TOTAL_ROWS * 256 * 2);
  unsigned short* Z3  = (unsigned short*)carve((size_t)TOTAL_ROWS * 256 * 2);
  float* part         = (float*)carve((size_t)512 * 512 * 4);
  float* ss           = (float*)carve(3 * 512 * 4);

  // merged prep: transposes + weight pack + xyz2 pack (1680 blocks)
  prep_all<<<dim3(1680), 256, 0, stream>>>(points2, p2t, points1, X1,
                                           fuse_w, e1_w, e2_w, Wb1, Wb2, Wb3,
                                           xyz2, sptg);

  // KNN + fused IDW gather -> X1 packed (K=384, cols 128..383)
  knn_gather<<<dim3(NPTS / 16, BATCH), 256, 0, stream>>>(xyz1, sptg, p2t, X1);

  // stage 1: fuse (K=384), raw input
  gemm_packed<384, false><<<dim3(512), 256, 0, stream>>>(Wb1, X1, nullptr, fuse_b, Z1, part);
  reduce_stats<<<dim3(64), 256, 0, stream>>>(part, fuse_g, fuse_be, ss);

  // stage 2: net1 (K=256), BN1+ReLU fused into X path
  gemm_packed<256, true><<<dim3(512), 256, 0, stream>>>(Wb2, Z1, ss, e1_b, Z2, part);
  reduce_stats<<<dim3(64), 256, 0, stream>>>(part, e1_g, e1_be, ss + 512);

  // stage 3: net2 (K=256), BN2+ReLU fused into X path
  gemm_packed<256, true><<<dim3(512), 256, 0, stream>>>(Wb3, Z2, ss + 512, e2_b, Z3, part);
  reduce_stats<<<dim3(64), 256, 0, stream>>>(part, e2_g, e2_be, ss + 1024);

  // final: BN3(Z3) + residual BN1(Z1) + ReLU + transpose to out
  bn_res_out<<<dim3(NPTS / 64, 4, BATCH), 256, 0, stream>>>(Z3, Z1, ss, ss + 1024, out);
}